// Round 1
// baseline (14286.621 us; speedup 1.0000x reference)
//
#include <hip/hip_runtime.h>
#include <cmath>

namespace {

constexpr int N = 100000;
constexpr int E = 1600000;
constexpr int S = 32;           // hidden
constexpr int R = 16;           // rbf
constexpr int L = 5;            // layers
constexpr float PI_F    = 3.14159265358979323846f;
constexpr float SQRT2_F = 1.41421356237309515f;

__device__ __forceinline__ float silu_f(float x) {
    return x / (1.0f + __expf(-x));
}

// ---------------------------------------------------------------- dist + deg
__global__ __launch_bounds__(256) void dist_deg_kernel(
    const int* __restrict__ ei, const float* __restrict__ pos,
    float* __restrict__ dist, int* __restrict__ deg)
{
    int e = blockIdx.x * 256 + threadIdx.x;
    if (e >= E) return;
    int r = ei[e];
    int c = ei[E + e];
    // posc = pos - mean(pos); the mean cancels in posc[r]-posc[c]
    float2 pr = reinterpret_cast<const float2*>(pos)[r];
    float2 pc = reinterpret_cast<const float2*>(pos)[c];
    float dx = pr.x - pc.x, dy = pr.y - pc.y;
    dist[e] = sqrtf(dx * dx + dy * dy);
    atomicAdd(&deg[r], 1);
}

// ---------------------------------------------------------------- node embed
__global__ __launch_bounds__(256) void node_embed_kernel(
    const float* __restrict__ u, const float* __restrict__ v,
    const float* __restrict__ bnorm, const float* __restrict__ yf,
    const float* __restrict__ Wn1, const float* __restrict__ bn1,
    const float* __restrict__ Wn2, const float* __restrict__ bn2,
    const int* __restrict__ deg, float* __restrict__ ivd,
    float* __restrict__ x)
{
    int n = blockIdx.x * 256 + threadIdx.x;
    if (n >= N) return;

    float f[10];
    float4 uu = reinterpret_cast<const float4*>(u)[n];
    f[0] = uu.x; f[1] = uu.y; f[2] = uu.z; f[3] = uu.w;
    float4 v0 = reinterpret_cast<const float4*>(v)[2 * n];
    float4 v1 = reinterpret_cast<const float4*>(v)[2 * n + 1];
    f[4] = sqrtf(v0.x * v0.x + v0.y * v0.y);
    f[5] = sqrtf(v0.z * v0.z + v0.w * v0.w);
    f[6] = sqrtf(v1.x * v1.x + v1.y * v1.y);
    f[7] = sqrtf(v1.z * v1.z + v1.w * v1.w);
    float2 bb = reinterpret_cast<const float2*>(bnorm)[n];
    f[8] = sqrtf(bb.x * bb.x + bb.y * bb.y);
    float2 yy = reinterpret_cast<const float2*>(yf)[n];
    f[9] = sqrtf(yy.x * yy.x + yy.y * yy.y);

    float h[64];
    #pragma unroll
    for (int j = 0; j < 64; ++j) h[j] = bn1[j];
    #pragma unroll
    for (int i = 0; i < 10; ++i) {
        float t = f[i];
        #pragma unroll
        for (int j = 0; j < 64; ++j) h[j] = fmaf(t, Wn1[i * 64 + j], h[j]);
    }
    #pragma unroll
    for (int j = 0; j < 64; ++j) h[j] = silu_f(h[j]);

    float o[32];
    #pragma unroll
    for (int j = 0; j < 32; ++j) o[j] = bn2[j];
    #pragma unroll
    for (int i = 0; i < 64; ++i) {
        float t = h[i];
        #pragma unroll
        for (int j = 0; j < 32; ++j) o[j] = fmaf(t, Wn2[i * 32 + j], o[j]);
    }
    float4* xo = reinterpret_cast<float4*>(x + (size_t)n * 32);
    #pragma unroll
    for (int i = 0; i < 8; ++i)
        xo[i] = make_float4(o[4 * i], o[4 * i + 1], o[4 * i + 2], o[4 * i + 3]);

    ivd[n] = 1.0f / fmaxf((float)deg[n], 1.0f);
}

// ---------------------------------------------------------------- edge MLP + scatter
__global__ __launch_bounds__(256) void edge_kernel(
    const int* __restrict__ ei, const float* __restrict__ dist,
    const float* __restrict__ x,
    const float* __restrict__ W1, const float* __restrict__ b1,
    const float* __restrict__ W2, const float* __restrict__ b2,
    float* __restrict__ agg)
{
    int e = blockIdx.x * 256 + threadIdx.x;
    if (e >= E) return;
    int r = ei[e];
    int c = ei[E + e];

    float h[32];
    #pragma unroll
    for (int j = 0; j < 32; ++j) h[j] = b1[j];

    // ef[0..31] = x[row]
    const float4* xr = reinterpret_cast<const float4*>(x + (size_t)r * 32);
    #pragma unroll 1
    for (int i = 0; i < 8; ++i) {
        float4 t = xr[i];
        const float* w = W1 + i * 4 * 32;
        #pragma unroll
        for (int j = 0; j < 32; ++j) h[j] = fmaf(t.x, w[j], h[j]);
        #pragma unroll
        for (int j = 0; j < 32; ++j) h[j] = fmaf(t.y, w[32 + j], h[j]);
        #pragma unroll
        for (int j = 0; j < 32; ++j) h[j] = fmaf(t.z, w[64 + j], h[j]);
        #pragma unroll
        for (int j = 0; j < 32; ++j) h[j] = fmaf(t.w, w[96 + j], h[j]);
    }
    // ef[32..63] = x[col]
    const float4* xc = reinterpret_cast<const float4*>(x + (size_t)c * 32);
    #pragma unroll 1
    for (int i = 0; i < 8; ++i) {
        float4 t = xc[i];
        const float* w = W1 + (32 + i * 4) * 32;
        #pragma unroll
        for (int j = 0; j < 32; ++j) h[j] = fmaf(t.x, w[j], h[j]);
        #pragma unroll
        for (int j = 0; j < 32; ++j) h[j] = fmaf(t.y, w[32 + j], h[j]);
        #pragma unroll
        for (int j = 0; j < 32; ++j) h[j] = fmaf(t.z, w[64 + j], h[j]);
        #pragma unroll
        for (int j = 0; j < 32; ++j) h[j] = fmaf(t.w, w[96 + j], h[j]);
    }
    // ef[64..79] = rbf(dist): sqrt(2)*sin(k*pi*d)/(d+eps), k=1..16 via recurrence
    float d = dist[e];
    float s1 = __sinf(PI_F * d);
    float c1 = __cosf(PI_F * d);
    float inv = SQRT2_F / (d + 1e-8f);
    float rb[16];
    {
        float skm = 0.0f, sk = s1;
        #pragma unroll
        for (int k = 0; k < 16; ++k) {
            rb[k] = sk * inv;
            float s2 = 2.0f * c1 * sk - skm;
            skm = sk; sk = s2;
        }
    }
    #pragma unroll
    for (int k = 0; k < 16; ++k) {
        const float* w = W1 + (64 + k) * 32;
        float t = rb[k];
        #pragma unroll
        for (int j = 0; j < 32; ++j) h[j] = fmaf(t, w[j], h[j]);
    }

    #pragma unroll
    for (int j = 0; j < 32; ++j) h[j] = silu_f(h[j]);

    float m[32];
    #pragma unroll
    for (int j = 0; j < 32; ++j) m[j] = b2[j];
    #pragma unroll
    for (int k = 0; k < 32; ++k) {
        float t = h[k];
        #pragma unroll
        for (int j = 0; j < 32; ++j) m[j] = fmaf(t, W2[k * 32 + j], m[j]);
    }

    float* ar = agg + (size_t)r * 32;
    #pragma unroll
    for (int j = 0; j < 32; ++j) unsafeAtomicAdd(ar + j, m[j]);
}

// ---------------------------------------------------------------- node update
__global__ __launch_bounds__(256) void node_update_kernel(
    const float* __restrict__ Wu1, const float* __restrict__ bu1,
    const float* __restrict__ Wu2, const float* __restrict__ bu2,
    const float* __restrict__ ivd, const float* __restrict__ agg,
    float* __restrict__ x)
{
    int n = blockIdx.x * 256 + threadIdx.x;
    if (n >= N) return;

    float h[32];
    #pragma unroll
    for (int j = 0; j < 32; ++j) h[j] = bu1[j];

    const float4* x4 = reinterpret_cast<const float4*>(x + (size_t)n * 32);
    #pragma unroll 1
    for (int i = 0; i < 8; ++i) {
        float4 t = x4[i];
        const float* w = Wu1 + i * 4 * 32;
        #pragma unroll
        for (int j = 0; j < 32; ++j) h[j] = fmaf(t.x, w[j], h[j]);
        #pragma unroll
        for (int j = 0; j < 32; ++j) h[j] = fmaf(t.y, w[32 + j], h[j]);
        #pragma unroll
        for (int j = 0; j < 32; ++j) h[j] = fmaf(t.z, w[64 + j], h[j]);
        #pragma unroll
        for (int j = 0; j < 32; ++j) h[j] = fmaf(t.w, w[96 + j], h[j]);
    }
    float sdeg = ivd[n];
    const float4* a4 = reinterpret_cast<const float4*>(agg + (size_t)n * 32);
    #pragma unroll 1
    for (int i = 0; i < 8; ++i) {
        float4 t = a4[i];
        t.x *= sdeg; t.y *= sdeg; t.z *= sdeg; t.w *= sdeg;
        const float* w = Wu1 + (32 + i * 4) * 32;
        #pragma unroll
        for (int j = 0; j < 32; ++j) h[j] = fmaf(t.x, w[j], h[j]);
        #pragma unroll
        for (int j = 0; j < 32; ++j) h[j] = fmaf(t.y, w[32 + j], h[j]);
        #pragma unroll
        for (int j = 0; j < 32; ++j) h[j] = fmaf(t.z, w[64 + j], h[j]);
        #pragma unroll
        for (int j = 0; j < 32; ++j) h[j] = fmaf(t.w, w[96 + j], h[j]);
    }
    #pragma unroll
    for (int j = 0; j < 32; ++j) h[j] = silu_f(h[j]);

    float o[32];
    #pragma unroll
    for (int j = 0; j < 32; ++j) o[j] = bu2[j];
    #pragma unroll
    for (int k = 0; k < 32; ++k) {
        float t = h[k];
        #pragma unroll
        for (int j = 0; j < 32; ++j) o[j] = fmaf(t, Wu2[k * 32 + j], o[j]);
    }
    // residual: x = x + o   (reload x, in-place per-thread safe)
    float* xw = x + (size_t)n * 32;
    float4* xw4 = reinterpret_cast<float4*>(xw);
    #pragma unroll
    for (int i = 0; i < 8; ++i) {
        float4 t = x4[i];
        t.x += o[4 * i]; t.y += o[4 * i + 1]; t.z += o[4 * i + 2]; t.w += o[4 * i + 3];
        xw4[i] = t;
    }
}

// ---------------------------------------------------------------- LN + heads
__global__ __launch_bounds__(256) void final_kernel(
    const float* __restrict__ x, const float* __restrict__ u,
    const float* __restrict__ v,
    const float* __restrict__ ln_g, const float* __restrict__ ln_b,
    const float* __restrict__ Wr1, const float* __restrict__ br1,
    const float* __restrict__ Wr2, const float* __restrict__ br2,
    const float* __restrict__ Ws1, const float* __restrict__ bs1,
    const float* __restrict__ Ws2, const float* __restrict__ bs2,
    float* __restrict__ out)
{
    int n = blockIdx.x * 256 + threadIdx.x;
    if (n >= N) return;

    float a[32];
    const float4* x4 = reinterpret_cast<const float4*>(x + (size_t)n * 32);
    #pragma unroll
    for (int i = 0; i < 8; ++i) {
        float4 t = x4[i];
        a[4 * i] = t.x; a[4 * i + 1] = t.y; a[4 * i + 2] = t.z; a[4 * i + 3] = t.w;
    }
    float mu = 0.0f;
    #pragma unroll
    for (int i = 0; i < 32; ++i) mu += a[i];
    mu *= (1.0f / 32.0f);
    float var = 0.0f;
    #pragma unroll
    for (int i = 0; i < 32; ++i) { float dlt = a[i] - mu; var += dlt * dlt; }
    var *= (1.0f / 32.0f);
    float rs = rsqrtf(var + 1e-5f);
    #pragma unroll
    for (int i = 0; i < 32; ++i) a[i] = (a[i] - mu) * rs * ln_g[i] + ln_b[i];

    float o0 = br2[0], o1 = br2[1], o2 = bs2[0];
    #pragma unroll 1
    for (int j = 0; j < 96; ++j) {
        float hr = br1[j];
        float hs = bs1[j];
        #pragma unroll
        for (int i = 0; i < 32; ++i) {
            hr = fmaf(a[i], Wr1[i * 96 + j], hr);
            hs = fmaf(a[i], Ws1[i * 96 + j], hs);
        }
        hr = silu_f(hr);
        hs = silu_f(hs);
        o0 = fmaf(hr, Wr2[2 * j], o0);
        o1 = fmaf(hr, Wr2[2 * j + 1], o1);
        o2 = fmaf(hs, Ws2[j], o2);
    }
    // out0 = u[:, -1] + u_head ; out1 = v_head + v[:, -1, :]
    out[n] = u[n * 4 + 3] + o2;
    out[N + 2 * n]     = o0 + v[n * 8 + 6];
    out[N + 2 * n + 1] = o1 + v[n * 8 + 7];
}

} // anonymous namespace

extern "C" void kernel_launch(void* const* d_in, const int* in_sizes, int n_in,
                              void* d_out, int out_size, void* d_ws, size_t ws_size,
                              hipStream_t stream)
{
    const float* u    = (const float*)d_in[0];
    const float* v    = (const float*)d_in[1];
    const float* bno  = (const float*)d_in[2];
    // d_in[3] = is_boundary (unused by forward)
    const float* yf   = (const float*)d_in[4];
    const float* pos  = (const float*)d_in[5];
    const int*   ei   = (const int*)d_in[6];
    const float* Wn1  = (const float*)d_in[7];
    const float* bn1  = (const float*)d_in[8];
    const float* Wn2  = (const float*)d_in[9];
    const float* bn2  = (const float*)d_in[10];
    const float* We1  = (const float*)d_in[11];
    const float* be1  = (const float*)d_in[12];
    const float* We2  = (const float*)d_in[13];
    const float* be2  = (const float*)d_in[14];
    const float* Wu1  = (const float*)d_in[15];
    const float* bu1  = (const float*)d_in[16];
    const float* Wu2  = (const float*)d_in[17];
    const float* bu2  = (const float*)d_in[18];
    const float* ln_g = (const float*)d_in[19];
    const float* ln_b = (const float*)d_in[20];
    const float* Wr1  = (const float*)d_in[21];
    const float* br1  = (const float*)d_in[22];
    const float* Wr2  = (const float*)d_in[23];
    const float* br2  = (const float*)d_in[24];
    const float* Ws1  = (const float*)d_in[25];
    const float* bs1  = (const float*)d_in[26];
    const float* Ws2  = (const float*)d_in[27];
    const float* bs2  = (const float*)d_in[28];
    float* out = (float*)d_out;

    // workspace layout (all 16B-aligned offsets)
    float* ws   = (float*)d_ws;
    float* dist = ws;                       // E floats
    int*   deg  = (int*)(ws + E);           // N ints
    float* ivd  = ws + E + N;               // N floats
    float* x    = ws + E + 2 * N;           // N*S floats
    float* agg  = x + (size_t)N * S;        // N*S floats

    const int egrid = (E + 255) / 256;
    const int ngrid = (N + 255) / 256;

    hipMemsetAsync(deg, 0, N * sizeof(int), stream);
    dist_deg_kernel<<<egrid, 256, 0, stream>>>(ei, pos, dist, deg);
    node_embed_kernel<<<ngrid, 256, 0, stream>>>(u, v, bno, yf, Wn1, bn1, Wn2, bn2,
                                                 deg, ivd, x);
    for (int l = 0; l < L; ++l) {
        hipMemsetAsync(agg, 0, (size_t)N * S * sizeof(float), stream);
        edge_kernel<<<egrid, 256, 0, stream>>>(ei, dist, x,
            We1 + (size_t)l * (2 * S + R) * S, be1 + (size_t)l * S,
            We2 + (size_t)l * S * S,           be2 + (size_t)l * S, agg);
        node_update_kernel<<<ngrid, 256, 0, stream>>>(
            Wu1 + (size_t)l * 2 * S * S, bu1 + (size_t)l * S,
            Wu2 + (size_t)l * S * S,     bu2 + (size_t)l * S, ivd, agg, x);
    }
    final_kernel<<<ngrid, 256, 0, stream>>>(x, u, v, ln_g, ln_b,
                                            Wr1, br1, Wr2, br2,
                                            Ws1, bs1, Ws2, bs2, out);
}

// Round 2
// 3686.438 us; speedup vs baseline: 3.8755x; 3.8755x over previous
//
#include <hip/hip_runtime.h>
#include <cmath>

namespace {

constexpr int N = 100000;
constexpr int E = 1600000;
constexpr int S = 32;           // hidden
constexpr int L = 5;            // layers
constexpr int NB = (N + 255) / 256;   // 391 blocks over nodes
constexpr float PI_F    = 3.14159265358979323846f;
constexpr float SQRT2_F = 1.41421356237309515f;

__device__ __forceinline__ float silu_f(float x) {
    return x / (1.0f + __expf(-x));
}

// h[j] += q.{x,y,z,w} * w[row..row+3][j]  (4 rows of 32)
__device__ __forceinline__ void fma4x32(float* h, float4 q, const float* __restrict__ w) {
    #pragma unroll
    for (int j = 0; j < 32; ++j) h[j] = fmaf(q.x, w[j], h[j]);
    #pragma unroll
    for (int j = 0; j < 32; ++j) h[j] = fmaf(q.y, w[32 + j], h[j]);
    #pragma unroll
    for (int j = 0; j < 32; ++j) h[j] = fmaf(q.z, w[64 + j], h[j]);
    #pragma unroll
    for (int j = 0; j < 32; ++j) h[j] = fmaf(q.w, w[96 + j], h[j]);
}

// ---------------------------------------------------------------- degree count
__global__ __launch_bounds__(256) void deg_kernel(
    const int* __restrict__ ei, int* __restrict__ deg)
{
    int e = blockIdx.x * 256 + threadIdx.x;
    if (e >= E) return;
    atomicAdd(&deg[ei[e]], 1);
}

// ---------------------------------------------------------------- scan (3-kernel hierarchical)
__global__ __launch_bounds__(256) void scanA(
    const int* __restrict__ deg, int* __restrict__ bsum)
{
    __shared__ int sd[256];
    int t = threadIdx.x;
    int n = blockIdx.x * 256 + t;
    sd[t] = (n < N) ? deg[n] : 0;
    __syncthreads();
    #pragma unroll
    for (int s = 128; s > 0; s >>= 1) {
        if (t < s) sd[t] += sd[t + s];
        __syncthreads();
    }
    if (t == 0) bsum[blockIdx.x] = sd[0];
}

__global__ __launch_bounds__(512) void scanB(int* __restrict__ bsum)
{
    __shared__ int sd[512];
    int t = threadIdx.x;
    sd[t] = (t < NB) ? bsum[t] : 0;
    __syncthreads();
    #pragma unroll
    for (int off = 1; off < 512; off <<= 1) {
        int v = (t >= off) ? sd[t - off] : 0;
        __syncthreads();
        sd[t] += v;
        __syncthreads();
    }
    if (t < NB) bsum[t] = (t == 0) ? 0 : sd[t - 1];   // exclusive
}

__global__ __launch_bounds__(256) void scanC(
    const int* __restrict__ deg, const int* __restrict__ bsum,
    int* __restrict__ start)
{
    __shared__ int sd[256];
    int t = threadIdx.x;
    int n = blockIdx.x * 256 + t;
    int v = (n < N) ? deg[n] : 0;
    sd[t] = v;
    __syncthreads();
    #pragma unroll
    for (int off = 1; off < 256; off <<= 1) {
        int w = (t >= off) ? sd[t - off] : 0;
        __syncthreads();
        sd[t] += w;
        __syncthreads();
    }
    if (n < N) start[n] = bsum[blockIdx.x] + sd[t] - v;  // exclusive
}

// ---------------------------------------------------------------- CSR fill (col + dist per slot)
__global__ __launch_bounds__(256) void fill_kernel(
    const int* __restrict__ ei, const float* __restrict__ pos,
    const int* __restrict__ start, int* __restrict__ cursor,
    int* __restrict__ csr_col, float* __restrict__ csr_dist)
{
    int e = blockIdx.x * 256 + threadIdx.x;
    if (e >= E) return;
    int r = ei[e];
    int c = ei[E + e];
    float2 pr = reinterpret_cast<const float2*>(pos)[r];
    float2 pc = reinterpret_cast<const float2*>(pos)[c];
    float dx = pr.x - pc.x, dy = pr.y - pc.y;
    float d = sqrtf(dx * dx + dy * dy);   // pos-mean cancels
    int k = atomicAdd(&cursor[r], 1);
    int s = start[r] + k;
    csr_col[s] = c;
    csr_dist[s] = d;
}

// ---------------------------------------------------------------- node embed
__global__ __launch_bounds__(256) void node_embed_kernel(
    const float* __restrict__ u, const float* __restrict__ v,
    const float* __restrict__ bnorm, const float* __restrict__ yf,
    const float* __restrict__ Wn1, const float* __restrict__ bn1,
    const float* __restrict__ Wn2, const float* __restrict__ bn2,
    float* __restrict__ x)
{
    int n = blockIdx.x * 256 + threadIdx.x;
    if (n >= N) return;

    float f[10];
    float4 uu = reinterpret_cast<const float4*>(u)[n];
    f[0] = uu.x; f[1] = uu.y; f[2] = uu.z; f[3] = uu.w;
    float4 v0 = reinterpret_cast<const float4*>(v)[2 * n];
    float4 v1 = reinterpret_cast<const float4*>(v)[2 * n + 1];
    f[4] = sqrtf(v0.x * v0.x + v0.y * v0.y);
    f[5] = sqrtf(v0.z * v0.z + v0.w * v0.w);
    f[6] = sqrtf(v1.x * v1.x + v1.y * v1.y);
    f[7] = sqrtf(v1.z * v1.z + v1.w * v1.w);
    float2 bb = reinterpret_cast<const float2*>(bnorm)[n];
    f[8] = sqrtf(bb.x * bb.x + bb.y * bb.y);
    float2 yy = reinterpret_cast<const float2*>(yf)[n];
    f[9] = sqrtf(yy.x * yy.x + yy.y * yy.y);

    float h[64];
    #pragma unroll
    for (int j = 0; j < 64; ++j) h[j] = bn1[j];
    #pragma unroll
    for (int i = 0; i < 10; ++i) {
        float t = f[i];
        #pragma unroll
        for (int j = 0; j < 64; ++j) h[j] = fmaf(t, Wn1[i * 64 + j], h[j]);
    }
    #pragma unroll
    for (int j = 0; j < 64; ++j) h[j] = silu_f(h[j]);

    float o[32];
    #pragma unroll
    for (int j = 0; j < 32; ++j) o[j] = bn2[j];
    #pragma unroll
    for (int i = 0; i < 64; ++i) {
        float t = h[i];
        #pragma unroll
        for (int j = 0; j < 32; ++j) o[j] = fmaf(t, Wn2[i * 32 + j], o[j]);
    }
    float4* xo = reinterpret_cast<float4*>(x + (size_t)n * 32);
    #pragma unroll
    for (int i = 0; i < 8; ++i)
        xo[i] = make_float4(o[4 * i], o[4 * i + 1], o[4 * i + 2], o[4 * i + 3]);
}

// ---------------------------------------------------------------- fused layer:
// per node: hbase = b1 + W1_row.x[n]; loop CSR edges accumulating
// sh = sum silu(hbase + W1_col.x[c] + W1_rbf.rbf(d)); agg = (sh@W2 + deg*b2)/deg;
// x_out = x + MLP_u([x, agg])
__global__ __launch_bounds__(256) void layer_kernel(
    const int* __restrict__ deg, const int* __restrict__ start,
    const int* __restrict__ csr_col, const float* __restrict__ csr_dist,
    const float* __restrict__ x_in, float* __restrict__ x_out,
    const float* __restrict__ W1, const float* __restrict__ b1,
    const float* __restrict__ W2, const float* __restrict__ b2,
    const float* __restrict__ Wu1, const float* __restrict__ bu1,
    const float* __restrict__ Wu2, const float* __restrict__ bu2)
{
    __shared__ float buf[32 * 256];   // [j][tid] streaming buffer, conflict-free
    int t = threadIdx.x;
    int n = blockIdx.x * 256 + t;
    if (n >= N) return;

    const float4* xi4 = reinterpret_cast<const float4*>(x_in + (size_t)n * 32);

    // hbase = b1 + W1[0:32,:].x[n]   (stream x[n] from global, chunked)
    float hb[32];
    #pragma unroll
    for (int j = 0; j < 32; ++j) hb[j] = b1[j];
    #pragma unroll 1
    for (int i = 0; i < 8; ++i) {
        float4 q = xi4[i];
        fma4x32(hb, q, W1 + i * 4 * 32);
    }

    float sh[32];
    #pragma unroll
    for (int j = 0; j < 32; ++j) sh[j] = 0.0f;

    int s0 = start[n];
    int dg = deg[n];
    #pragma unroll 1
    for (int s = s0; s < s0 + dg; ++s) {
        int c = csr_col[s];
        float d = csr_dist[s];
        const float4* xc4 = reinterpret_cast<const float4*>(x_in + (size_t)c * 32);
        float4 q0 = xc4[0], q1 = xc4[1], q2 = xc4[2], q3 = xc4[3];
        float4 q4 = xc4[4], q5 = xc4[5], q6 = xc4[6], q7 = xc4[7];

        float h[32];
        #pragma unroll
        for (int j = 0; j < 32; ++j) h[j] = hb[j];
        fma4x32(h, q0, W1 + 32 * 32);
        fma4x32(h, q1, W1 + 36 * 32);
        fma4x32(h, q2, W1 + 40 * 32);
        fma4x32(h, q3, W1 + 44 * 32);
        fma4x32(h, q4, W1 + 48 * 32);
        fma4x32(h, q5, W1 + 52 * 32);
        fma4x32(h, q6, W1 + 56 * 32);
        fma4x32(h, q7, W1 + 60 * 32);

        // rbf(d): sqrt(2)*sin(k*pi*d)/(d+eps), k=1..16 via sin recurrence
        float s1 = __sinf(PI_F * d);
        float c1 = __cosf(PI_F * d);
        float inv = SQRT2_F / (d + 1e-8f);
        float tc = 2.0f * c1;
        float sk = s1, skm = 0.0f;
        #pragma unroll
        for (int k = 0; k < 16; ++k) {
            float rbv = sk * inv;
            const float* w = W1 + (64 + k) * 32;
            #pragma unroll
            for (int j = 0; j < 32; ++j) h[j] = fmaf(rbv, w[j], h[j]);
            float s2 = tc * sk - skm; skm = sk; sk = s2;
        }
        #pragma unroll
        for (int j = 0; j < 32; ++j) sh[j] += silu_f(h[j]);
    }

    // agg = (sh @ W2 + deg*b2) * inv_deg    (stream sh via LDS)
    #pragma unroll
    for (int j = 0; j < 32; ++j) buf[j * 256 + t] = sh[j];
    float fdg = (float)dg;
    float ag[32];
    #pragma unroll
    for (int j = 0; j < 32; ++j) ag[j] = fdg * b2[j];
    #pragma unroll 1
    for (int k = 0; k < 32; ++k) {
        float tv = buf[k * 256 + t];
        const float* w = W2 + k * 32;
        #pragma unroll
        for (int j = 0; j < 32; ++j) ag[j] = fmaf(tv, w[j], ag[j]);
    }
    float ivd = 1.0f / fmaxf(fdg, 1.0f);
    #pragma unroll
    for (int j = 0; j < 32; ++j) ag[j] *= ivd;

    // node update: hu = silu(bu1 + Wu1.[x, agg]) ; o = bu2 + Wu2.hu ; x_out = x + o
    #pragma unroll
    for (int j = 0; j < 32; ++j) buf[j * 256 + t] = ag[j];
    float hu[32];
    #pragma unroll
    for (int j = 0; j < 32; ++j) hu[j] = bu1[j];
    #pragma unroll 1
    for (int i = 0; i < 8; ++i) {
        float4 q = xi4[i];
        fma4x32(hu, q, Wu1 + i * 4 * 32);
    }
    #pragma unroll 1
    for (int i = 0; i < 32; ++i) {
        float tv = buf[i * 256 + t];
        const float* w = Wu1 + (32 + i) * 32;
        #pragma unroll
        for (int j = 0; j < 32; ++j) hu[j] = fmaf(tv, w[j], hu[j]);
    }
    #pragma unroll
    for (int j = 0; j < 32; ++j) hu[j] = silu_f(hu[j]);

    #pragma unroll
    for (int j = 0; j < 32; ++j) buf[j * 256 + t] = hu[j];
    float o[32];
    #pragma unroll
    for (int j = 0; j < 32; ++j) o[j] = bu2[j];
    #pragma unroll 1
    for (int k = 0; k < 32; ++k) {
        float tv = buf[k * 256 + t];
        const float* w = Wu2 + k * 32;
        #pragma unroll
        for (int j = 0; j < 32; ++j) o[j] = fmaf(tv, w[j], o[j]);
    }

    float4* xo4 = reinterpret_cast<float4*>(x_out + (size_t)n * 32);
    #pragma unroll
    for (int i = 0; i < 8; ++i) {
        float4 q = xi4[i];
        xo4[i] = make_float4(q.x + o[4 * i], q.y + o[4 * i + 1],
                             q.z + o[4 * i + 2], q.w + o[4 * i + 3]);
    }
}

// ---------------------------------------------------------------- LN + heads
__global__ __launch_bounds__(256) void final_kernel(
    const float* __restrict__ x, const float* __restrict__ u,
    const float* __restrict__ v,
    const float* __restrict__ ln_g, const float* __restrict__ ln_b,
    const float* __restrict__ Wr1, const float* __restrict__ br1,
    const float* __restrict__ Wr2, const float* __restrict__ br2,
    const float* __restrict__ Ws1, const float* __restrict__ bs1,
    const float* __restrict__ Ws2, const float* __restrict__ bs2,
    float* __restrict__ out)
{
    int n = blockIdx.x * 256 + threadIdx.x;
    if (n >= N) return;

    float a[32];
    const float4* x4 = reinterpret_cast<const float4*>(x + (size_t)n * 32);
    #pragma unroll
    for (int i = 0; i < 8; ++i) {
        float4 t = x4[i];
        a[4 * i] = t.x; a[4 * i + 1] = t.y; a[4 * i + 2] = t.z; a[4 * i + 3] = t.w;
    }
    float mu = 0.0f;
    #pragma unroll
    for (int i = 0; i < 32; ++i) mu += a[i];
    mu *= (1.0f / 32.0f);
    float var = 0.0f;
    #pragma unroll
    for (int i = 0; i < 32; ++i) { float dlt = a[i] - mu; var += dlt * dlt; }
    var *= (1.0f / 32.0f);
    float rs = rsqrtf(var + 1e-5f);
    #pragma unroll
    for (int i = 0; i < 32; ++i) a[i] = (a[i] - mu) * rs * ln_g[i] + ln_b[i];

    float o0 = br2[0], o1 = br2[1], o2 = bs2[0];
    #pragma unroll 1
    for (int j = 0; j < 96; ++j) {
        float hr = br1[j];
        float hs = bs1[j];
        #pragma unroll
        for (int i = 0; i < 32; ++i) {
            hr = fmaf(a[i], Wr1[i * 96 + j], hr);
            hs = fmaf(a[i], Ws1[i * 96 + j], hs);
        }
        hr = silu_f(hr);
        hs = silu_f(hs);
        o0 = fmaf(hr, Wr2[2 * j], o0);
        o1 = fmaf(hr, Wr2[2 * j + 1], o1);
        o2 = fmaf(hs, Ws2[j], o2);
    }
    out[n] = u[n * 4 + 3] + o2;
    out[N + 2 * n]     = o0 + v[n * 8 + 6];
    out[N + 2 * n + 1] = o1 + v[n * 8 + 7];
}

} // anonymous namespace

extern "C" void kernel_launch(void* const* d_in, const int* in_sizes, int n_in,
                              void* d_out, int out_size, void* d_ws, size_t ws_size,
                              hipStream_t stream)
{
    const float* u    = (const float*)d_in[0];
    const float* v    = (const float*)d_in[1];
    const float* bno  = (const float*)d_in[2];
    const float* yf   = (const float*)d_in[4];
    const float* pos  = (const float*)d_in[5];
    const int*   ei   = (const int*)d_in[6];
    const float* Wn1  = (const float*)d_in[7];
    const float* bn1  = (const float*)d_in[8];
    const float* Wn2  = (const float*)d_in[9];
    const float* bn2  = (const float*)d_in[10];
    const float* We1  = (const float*)d_in[11];
    const float* be1  = (const float*)d_in[12];
    const float* We2  = (const float*)d_in[13];
    const float* be2  = (const float*)d_in[14];
    const float* Wu1  = (const float*)d_in[15];
    const float* bu1  = (const float*)d_in[16];
    const float* Wu2  = (const float*)d_in[17];
    const float* bu2  = (const float*)d_in[18];
    const float* ln_g = (const float*)d_in[19];
    const float* ln_b = (const float*)d_in[20];
    const float* Wr1  = (const float*)d_in[21];
    const float* br1  = (const float*)d_in[22];
    const float* Wr2  = (const float*)d_in[23];
    const float* br2  = (const float*)d_in[24];
    const float* Ws1  = (const float*)d_in[25];
    const float* bs1  = (const float*)d_in[26];
    const float* Ws2  = (const float*)d_in[27];
    const float* bs2  = (const float*)d_in[28];
    float* out = (float*)d_out;

    // workspace layout
    int*   deg      = (int*)d_ws;                    // N
    int*   cursor   = deg + N;                       // N
    int*   start    = cursor + N;                    // N
    int*   bsum     = start + N;                     // 512
    int*   csr_col  = bsum + 512;                    // E
    float* csr_dist = (float*)(csr_col + E);         // E
    float* x0       = csr_dist + E;                  // N*S  (16B-aligned)
    float* x1       = x0 + (size_t)N * S;            // N*S

    const int egrid = (E + 255) / 256;

    hipMemsetAsync(deg, 0, 2 * N * sizeof(int), stream);   // deg + cursor
    deg_kernel<<<egrid, 256, 0, stream>>>(ei, deg);
    scanA<<<NB, 256, 0, stream>>>(deg, bsum);
    scanB<<<1, 512, 0, stream>>>(bsum);
    scanC<<<NB, 256, 0, stream>>>(deg, bsum, start);
    fill_kernel<<<egrid, 256, 0, stream>>>(ei, pos, start, cursor, csr_col, csr_dist);

    node_embed_kernel<<<NB, 256, 0, stream>>>(u, v, bno, yf, Wn1, bn1, Wn2, bn2, x0);

    float* xin = x0;
    float* xout = x1;
    for (int l = 0; l < L; ++l) {
        layer_kernel<<<NB, 256, 0, stream>>>(
            deg, start, csr_col, csr_dist, xin, xout,
            We1 + (size_t)l * 80 * 32, be1 + (size_t)l * 32,
            We2 + (size_t)l * 32 * 32, be2 + (size_t)l * 32,
            Wu1 + (size_t)l * 64 * 32, bu1 + (size_t)l * 32,
            Wu2 + (size_t)l * 32 * 32, bu2 + (size_t)l * 32);
        float* tmp = xin; xin = xout; xout = tmp;
    }

    final_kernel<<<NB, 256, 0, stream>>>(xin, u, v, ln_g, ln_b,
                                         Wr1, br1, Wr2, br2,
                                         Ws1, bs1, Ws2, bs2, out);
}

// Round 3
// 3497.713 us; speedup vs baseline: 4.0846x; 1.0540x over previous
//
#include <hip/hip_runtime.h>
#include <cmath>

namespace {

constexpr int N = 100000;
constexpr int E = 1600000;
constexpr int S = 32;           // hidden
constexpr int L = 5;            // layers
constexpr int NB = (N + 255) / 256;   // 391 blocks (node-per-thread kernels)
constexpr int LB = (N + 63) / 64;     // 1563 blocks (layer kernel: 64 nodes/block)
constexpr float PI_F    = 3.14159265358979323846f;
constexpr float SQRT2_F = 1.41421356237309515f;

__device__ __forceinline__ float silu_f(float x) {
    return x / (1.0f + __expf(-x));
}

// h[0..15] += a * w[0..15]  (w wave-uniform -> scalar loads)
__device__ __forceinline__ void fma16(float* h, float a, const float* __restrict__ w) {
    #pragma unroll
    for (int j = 0; j < 16; ++j) h[j] = fmaf(a, w[j], h[j]);
}

// ---------------------------------------------------------------- degree count
__global__ __launch_bounds__(256) void deg_kernel(
    const int* __restrict__ ei, int* __restrict__ deg)
{
    int e = blockIdx.x * 256 + threadIdx.x;
    if (e >= E) return;
    atomicAdd(&deg[ei[e]], 1);
}

// ---------------------------------------------------------------- scan (3-kernel hierarchical)
__global__ __launch_bounds__(256) void scanA(
    const int* __restrict__ deg, int* __restrict__ bsum)
{
    __shared__ int sd[256];
    int t = threadIdx.x;
    int n = blockIdx.x * 256 + t;
    sd[t] = (n < N) ? deg[n] : 0;
    __syncthreads();
    #pragma unroll
    for (int s = 128; s > 0; s >>= 1) {
        if (t < s) sd[t] += sd[t + s];
        __syncthreads();
    }
    if (t == 0) bsum[blockIdx.x] = sd[0];
}

__global__ __launch_bounds__(512) void scanB(int* __restrict__ bsum)
{
    __shared__ int sd[512];
    int t = threadIdx.x;
    sd[t] = (t < NB) ? bsum[t] : 0;
    __syncthreads();
    #pragma unroll
    for (int off = 1; off < 512; off <<= 1) {
        int v = (t >= off) ? sd[t - off] : 0;
        __syncthreads();
        sd[t] += v;
        __syncthreads();
    }
    if (t < NB) bsum[t] = (t == 0) ? 0 : sd[t - 1];   // exclusive
}

__global__ __launch_bounds__(256) void scanC(
    const int* __restrict__ deg, const int* __restrict__ bsum,
    int* __restrict__ start)
{
    __shared__ int sd[256];
    int t = threadIdx.x;
    int n = blockIdx.x * 256 + t;
    int v = (n < N) ? deg[n] : 0;
    sd[t] = v;
    __syncthreads();
    #pragma unroll
    for (int off = 1; off < 256; off <<= 1) {
        int w = (t >= off) ? sd[t - off] : 0;
        __syncthreads();
        sd[t] += w;
        __syncthreads();
    }
    if (n < N) start[n] = bsum[blockIdx.x] + sd[t] - v;  // exclusive
}

// ---------------------------------------------------------------- CSR fill
__global__ __launch_bounds__(256) void fill_kernel(
    const int* __restrict__ ei, const float* __restrict__ pos,
    const int* __restrict__ start, int* __restrict__ cursor,
    int* __restrict__ csr_col, float* __restrict__ csr_dist)
{
    int e = blockIdx.x * 256 + threadIdx.x;
    if (e >= E) return;
    int r = ei[e];
    int c = ei[E + e];
    float2 pr = reinterpret_cast<const float2*>(pos)[r];
    float2 pc = reinterpret_cast<const float2*>(pos)[c];
    float dx = pr.x - pc.x, dy = pr.y - pc.y;
    float d = sqrtf(dx * dx + dy * dy);   // pos-mean cancels
    int k = atomicAdd(&cursor[r], 1);
    int s = start[r] + k;
    csr_col[s] = c;
    csr_dist[s] = d;
}

// ---------------------------------------------------------------- node embed
__global__ __launch_bounds__(256) void node_embed_kernel(
    const float* __restrict__ u, const float* __restrict__ v,
    const float* __restrict__ bnorm, const float* __restrict__ yf,
    const float* __restrict__ Wn1, const float* __restrict__ bn1,
    const float* __restrict__ Wn2, const float* __restrict__ bn2,
    float* __restrict__ x)
{
    int n = blockIdx.x * 256 + threadIdx.x;
    if (n >= N) return;

    float f[10];
    float4 uu = reinterpret_cast<const float4*>(u)[n];
    f[0] = uu.x; f[1] = uu.y; f[2] = uu.z; f[3] = uu.w;
    float4 v0 = reinterpret_cast<const float4*>(v)[2 * n];
    float4 v1 = reinterpret_cast<const float4*>(v)[2 * n + 1];
    f[4] = sqrtf(v0.x * v0.x + v0.y * v0.y);
    f[5] = sqrtf(v0.z * v0.z + v0.w * v0.w);
    f[6] = sqrtf(v1.x * v1.x + v1.y * v1.y);
    f[7] = sqrtf(v1.z * v1.z + v1.w * v1.w);
    float2 bb = reinterpret_cast<const float2*>(bnorm)[n];
    f[8] = sqrtf(bb.x * bb.x + bb.y * bb.y);
    float2 yy = reinterpret_cast<const float2*>(yf)[n];
    f[9] = sqrtf(yy.x * yy.x + yy.y * yy.y);

    float h[64];
    #pragma unroll
    for (int j = 0; j < 64; ++j) h[j] = bn1[j];
    #pragma unroll
    for (int i = 0; i < 10; ++i) {
        float t = f[i];
        #pragma unroll
        for (int j = 0; j < 64; ++j) h[j] = fmaf(t, Wn1[i * 64 + j], h[j]);
    }
    #pragma unroll
    for (int j = 0; j < 64; ++j) h[j] = silu_f(h[j]);

    float o[32];
    #pragma unroll
    for (int j = 0; j < 32; ++j) o[j] = bn2[j];
    #pragma unroll
    for (int i = 0; i < 64; ++i) {
        float t = h[i];
        #pragma unroll
        for (int j = 0; j < 32; ++j) o[j] = fmaf(t, Wn2[i * 32 + j], o[j]);
    }
    float4* xo = reinterpret_cast<float4*>(x + (size_t)n * 32);
    #pragma unroll
    for (int i = 0; i < 8; ++i)
        xo[i] = make_float4(o[4 * i], o[4 * i + 1], o[4 * i + 2], o[4 * i + 3]);
}

// ---------------------------------------------------------------- fused layer (4 lanes per node)
// wave w (0..3): ph = w&1 (output half, wave-uniform -> scalar weight loads)
//                nodes nl = (w>>1)*32 + (lane>>1), pe = lane&1 (edge half)
__global__ __launch_bounds__(256) void layer_kernel(
    const int* __restrict__ deg, const int* __restrict__ start,
    const int* __restrict__ csr_col, const float* __restrict__ csr_dist,
    const float* __restrict__ x_in, float* __restrict__ x_out,
    const float* __restrict__ W1, const float* __restrict__ b1,
    const float* __restrict__ W2, const float* __restrict__ b2,
    const float* __restrict__ Wu1, const float* __restrict__ bu1,
    const float* __restrict__ Wu2, const float* __restrict__ bu2)
{
    __shared__ float exA[64][32];   // 8 KB exchange buffer A
    __shared__ float exB[64][32];   // 8 KB exchange buffer B

    int t = threadIdx.x;
    int w = t >> 6;
    int lane = t & 63;
    int ph = w & 1;                  // wave-uniform output half
    int jo = ph * 16;
    int joo = jo ^ 16;               // other half offset
    int nl = (w >> 1) * 32 + (lane >> 1);
    int pe = lane & 1;
    int n = blockIdx.x * 64 + nl;
    bool valid = (n < N);
    size_t ns = valid ? (size_t)n : 0;

    const float4* xi4 = reinterpret_cast<const float4*>(x_in + ns * 32);

    // ---- hbase[16] = b1h + W1[0:32, half].x[n]
    float hb[16];
    #pragma unroll
    for (int j = 0; j < 16; ++j) hb[j] = b1[jo + j];
    {
        const float* wb = W1 + jo;
        #pragma unroll 1
        for (int i = 0; i < 8; ++i) {
            float4 q = xi4[i];
            const float* wr = wb + i * 4 * 32;
            fma16(hb, q.x, wr);
            fma16(hb, q.y, wr + 32);
            fma16(hb, q.z, wr + 64);
            fma16(hb, q.w, wr + 96);
        }
    }

    // ---- edge loop (pe-strided)
    float sh[16];
    #pragma unroll
    for (int j = 0; j < 16; ++j) sh[j] = 0.0f;

    int s0 = valid ? start[n] : 0;
    int dg = valid ? deg[n] : 0;
    const float* W1c = W1 + 32 * 32 + jo;   // x[col] rows
    const float* W1r = W1 + 64 * 32 + jo;   // rbf rows
    #pragma unroll 1
    for (int s = s0 + pe; s < s0 + dg; s += 2) {
        int c = csr_col[s];
        float d = csr_dist[s];
        const float4* xc4 = reinterpret_cast<const float4*>(x_in + (size_t)c * 32);

        float h[16];
        #pragma unroll
        for (int j = 0; j < 16; ++j) h[j] = hb[j];

        #pragma unroll 1
        for (int ch = 0; ch < 2; ++ch) {
            float4 a0 = xc4[ch * 4 + 0];
            float4 a1 = xc4[ch * 4 + 1];
            float4 a2 = xc4[ch * 4 + 2];
            float4 a3 = xc4[ch * 4 + 3];
            const float* wr = W1c + ch * 16 * 32;
            fma16(h, a0.x, wr);           fma16(h, a0.y, wr + 32);
            fma16(h, a0.z, wr + 64);      fma16(h, a0.w, wr + 96);
            fma16(h, a1.x, wr + 128);     fma16(h, a1.y, wr + 160);
            fma16(h, a1.z, wr + 192);     fma16(h, a1.w, wr + 224);
            fma16(h, a2.x, wr + 256);     fma16(h, a2.y, wr + 288);
            fma16(h, a2.z, wr + 320);     fma16(h, a2.w, wr + 352);
            fma16(h, a3.x, wr + 384);     fma16(h, a3.y, wr + 416);
            fma16(h, a3.z, wr + 448);     fma16(h, a3.w, wr + 480);
        }

        // rbf(d): sqrt(2)*sin(k*pi*d)/(d+eps), k=1..16 via sin recurrence
        float s1 = __sinf(PI_F * d);
        float c1 = __cosf(PI_F * d);
        float inv = SQRT2_F / (d + 1e-8f);
        float tc = 2.0f * c1;
        float sk = s1, skm = 0.0f;
        #pragma unroll
        for (int k = 0; k < 16; ++k) {
            fma16(h, sk * inv, W1r + k * 32);
            float s2 = tc * sk - skm; skm = sk; sk = s2;
        }

        #pragma unroll
        for (int j = 0; j < 16; ++j) sh[j] += silu_f(h[j]);
    }

    // ---- merge pe halves (adjacent lanes)
    #pragma unroll
    for (int j = 0; j < 16; ++j) sh[j] += __shfl_xor(sh[j], 1, 64);

    // ---- agg = (sh @ W2 + deg*b2) / deg : partials over own sh rows for both output halves
    float pa_own[16], pa_oth[16];
    #pragma unroll
    for (int j = 0; j < 16; ++j) { pa_own[j] = 0.0f; pa_oth[j] = 0.0f; }
    #pragma unroll 1
    for (int kk = 0; kk < 16; ++kk) {
        float sv = sh[kk];
        const float* wr = W2 + (jo + kk) * 32;
        fma16(pa_own, sv, wr + jo);
        fma16(pa_oth, sv, wr + joo);
    }
    if (pe == 0) {
        #pragma unroll
        for (int j = 0; j < 16; ++j) exA[nl][joo + j] = pa_oth[j];
    }
    __syncthreads();

    float fdg = (float)dg;
    float ivd = 1.0f / fmaxf(fdg, 1.0f);
    float ag[16];
    #pragma unroll
    for (int j = 0; j < 16; ++j)
        ag[j] = (pa_own[j] + exA[nl][jo + j] + fdg * b2[jo + j]) * ivd;

    if (pe == 0) {
        #pragma unroll
        for (int j = 0; j < 16; ++j) exB[nl][jo + j] = ag[j];
    }
    __syncthreads();
    float agо[16];
    #pragma unroll
    for (int j = 0; j < 16; ++j) agо[j] = exB[nl][joo + j];

    // ---- node update: hu = silu(bu1h + Wu1[x(32); agg(32)] half)
    float hu[16];
    #pragma unroll
    for (int j = 0; j < 16; ++j) hu[j] = bu1[jo + j];
    {
        const float* wb = Wu1 + jo;
        #pragma unroll 1
        for (int i = 0; i < 8; ++i) {
            float4 q = xi4[i];
            const float* wr = wb + i * 4 * 32;
            fma16(hu, q.x, wr);
            fma16(hu, q.y, wr + 32);
            fma16(hu, q.z, wr + 64);
            fma16(hu, q.w, wr + 96);
        }
        const float* wro = Wu1 + (32 + jo) * 32 + jo;   // own agg rows
        const float* wrx = Wu1 + (32 + joo) * 32 + jo;  // other agg rows
        #pragma unroll 1
        for (int kk = 0; kk < 16; ++kk) {
            fma16(hu, ag[kk],  wro + kk * 32);
            fma16(hu, agо[kk], wrx + kk * 32);
        }
    }
    #pragma unroll
    for (int j = 0; j < 16; ++j) hu[j] = silu_f(hu[j]);

    __syncthreads();   // WAR on exA
    if (pe == 0) {
        #pragma unroll
        for (int j = 0; j < 16; ++j) exA[nl][jo + j] = hu[j];
    }
    __syncthreads();

    // ---- o = bu2h + Wu2.hu(32) ; x_out = x + o
    float o[16];
    #pragma unroll
    for (int j = 0; j < 16; ++j) o[j] = bu2[jo + j];
    {
        const float* wro = Wu2 + jo * 32 + jo;
        #pragma unroll 1
        for (int kk = 0; kk < 16; ++kk)
            fma16(o, hu[kk], wro + kk * 32);
        const float* wrx = Wu2 + joo * 32 + jo;
        #pragma unroll 1
        for (int kk = 0; kk < 16; ++kk)
            fma16(o, exA[nl][joo + kk], wrx + kk * 32);
    }

    if (valid) {
        // lane writes 8 floats: dims [jo + pe*8, +8)
        float ov[8];
        #pragma unroll
        for (int j = 0; j < 8; ++j) ov[j] = pe ? o[8 + j] : o[j];
        const float4* xi = reinterpret_cast<const float4*>(x_in + (size_t)n * 32 + jo + pe * 8);
        float4* xo = reinterpret_cast<float4*>(x_out + (size_t)n * 32 + jo + pe * 8);
        float4 r0 = xi[0], r1 = xi[1];
        xo[0] = make_float4(r0.x + ov[0], r0.y + ov[1], r0.z + ov[2], r0.w + ov[3]);
        xo[1] = make_float4(r1.x + ov[4], r1.y + ov[5], r1.z + ov[6], r1.w + ov[7]);
    }
}

// ---------------------------------------------------------------- LN + heads
__global__ __launch_bounds__(256) void final_kernel(
    const float* __restrict__ x, const float* __restrict__ u,
    const float* __restrict__ v,
    const float* __restrict__ ln_g, const float* __restrict__ ln_b,
    const float* __restrict__ Wr1, const float* __restrict__ br1,
    const float* __restrict__ Wr2, const float* __restrict__ br2,
    const float* __restrict__ Ws1, const float* __restrict__ bs1,
    const float* __restrict__ Ws2, const float* __restrict__ bs2,
    float* __restrict__ out)
{
    int n = blockIdx.x * 256 + threadIdx.x;
    if (n >= N) return;

    float a[32];
    const float4* x4 = reinterpret_cast<const float4*>(x + (size_t)n * 32);
    #pragma unroll
    for (int i = 0; i < 8; ++i) {
        float4 t = x4[i];
        a[4 * i] = t.x; a[4 * i + 1] = t.y; a[4 * i + 2] = t.z; a[4 * i + 3] = t.w;
    }
    float mu = 0.0f;
    #pragma unroll
    for (int i = 0; i < 32; ++i) mu += a[i];
    mu *= (1.0f / 32.0f);
    float var = 0.0f;
    #pragma unroll
    for (int i = 0; i < 32; ++i) { float dlt = a[i] - mu; var += dlt * dlt; }
    var *= (1.0f / 32.0f);
    float rs = rsqrtf(var + 1e-5f);
    #pragma unroll
    for (int i = 0; i < 32; ++i) a[i] = (a[i] - mu) * rs * ln_g[i] + ln_b[i];

    float o0 = br2[0], o1 = br2[1], o2 = bs2[0];
    #pragma unroll 1
    for (int j = 0; j < 96; ++j) {
        float hr = br1[j];
        float hs = bs1[j];
        #pragma unroll
        for (int i = 0; i < 32; ++i) {
            hr = fmaf(a[i], Wr1[i * 96 + j], hr);
            hs = fmaf(a[i], Ws1[i * 96 + j], hs);
        }
        hr = silu_f(hr);
        hs = silu_f(hs);
        o0 = fmaf(hr, Wr2[2 * j], o0);
        o1 = fmaf(hr, Wr2[2 * j + 1], o1);
        o2 = fmaf(hs, Ws2[j], o2);
    }
    out[n] = u[n * 4 + 3] + o2;
    out[N + 2 * n]     = o0 + v[n * 8 + 6];
    out[N + 2 * n + 1] = o1 + v[n * 8 + 7];
}

} // anonymous namespace

extern "C" void kernel_launch(void* const* d_in, const int* in_sizes, int n_in,
                              void* d_out, int out_size, void* d_ws, size_t ws_size,
                              hipStream_t stream)
{
    const float* u    = (const float*)d_in[0];
    const float* v    = (const float*)d_in[1];
    const float* bno  = (const float*)d_in[2];
    const float* yf   = (const float*)d_in[4];
    const float* pos  = (const float*)d_in[5];
    const int*   ei   = (const int*)d_in[6];
    const float* Wn1  = (const float*)d_in[7];
    const float* bn1  = (const float*)d_in[8];
    const float* Wn2  = (const float*)d_in[9];
    const float* bn2  = (const float*)d_in[10];
    const float* We1  = (const float*)d_in[11];
    const float* be1  = (const float*)d_in[12];
    const float* We2  = (const float*)d_in[13];
    const float* be2  = (const float*)d_in[14];
    const float* Wu1  = (const float*)d_in[15];
    const float* bu1  = (const float*)d_in[16];
    const float* Wu2  = (const float*)d_in[17];
    const float* bu2  = (const float*)d_in[18];
    const float* ln_g = (const float*)d_in[19];
    const float* ln_b = (const float*)d_in[20];
    const float* Wr1  = (const float*)d_in[21];
    const float* br1  = (const float*)d_in[22];
    const float* Wr2  = (const float*)d_in[23];
    const float* br2  = (const float*)d_in[24];
    const float* Ws1  = (const float*)d_in[25];
    const float* bs1  = (const float*)d_in[26];
    const float* Ws2  = (const float*)d_in[27];
    const float* bs2  = (const float*)d_in[28];
    float* out = (float*)d_out;

    // workspace layout
    int*   deg      = (int*)d_ws;                    // N
    int*   cursor   = deg + N;                       // N
    int*   start    = cursor + N;                    // N
    int*   bsum     = start + N;                     // 512
    int*   csr_col  = bsum + 512;                    // E
    float* csr_dist = (float*)(csr_col + E);         // E
    float* x0       = csr_dist + E;                  // N*S
    float* x1       = x0 + (size_t)N * S;            // N*S

    const int egrid = (E + 255) / 256;

    hipMemsetAsync(deg, 0, 2 * N * sizeof(int), stream);   // deg + cursor
    deg_kernel<<<egrid, 256, 0, stream>>>(ei, deg);
    scanA<<<NB, 256, 0, stream>>>(deg, bsum);
    scanB<<<1, 512, 0, stream>>>(bsum);
    scanC<<<NB, 256, 0, stream>>>(deg, bsum, start);
    fill_kernel<<<egrid, 256, 0, stream>>>(ei, pos, start, cursor, csr_col, csr_dist);

    node_embed_kernel<<<NB, 256, 0, stream>>>(u, v, bno, yf, Wn1, bn1, Wn2, bn2, x0);

    float* xin = x0;
    float* xout = x1;
    for (int l = 0; l < L; ++l) {
        layer_kernel<<<LB, 256, 0, stream>>>(
            deg, start, csr_col, csr_dist, xin, xout,
            We1 + (size_t)l * 80 * 32, be1 + (size_t)l * 32,
            We2 + (size_t)l * 32 * 32, be2 + (size_t)l * 32,
            Wu1 + (size_t)l * 64 * 32, bu1 + (size_t)l * 32,
            Wu2 + (size_t)l * 32 * 32, bu2 + (size_t)l * 32);
        float* tmp = xin; xin = xout; xout = tmp;
    }

    final_kernel<<<NB, 256, 0, stream>>>(xin, u, v, ln_g, ln_b,
                                         Wr1, br1, Wr2, br2,
                                         Ws1, bs1, Ws2, bs2, out);
}

// Round 4
// 2563.350 us; speedup vs baseline: 5.5734x; 1.3645x over previous
//
#include <hip/hip_runtime.h>
#include <cmath>

namespace {

constexpr int N = 100000;
constexpr int E = 1600000;
constexpr int S = 32;           // hidden
constexpr int L = 5;            // layers
constexpr int NB = (N + 255) / 256;   // 391 blocks (node-per-thread kernels)
constexpr int LB = (N + 63) / 64;     // 1563 blocks (layer kernel: 64 nodes/block)
constexpr float PI_F    = 3.14159265358979323846f;
constexpr float SQRT2_F = 1.41421356237309515f;

__device__ __forceinline__ float silu_f(float x) {
    return x / (1.0f + __expf(-x));
}

// h[0..15] += a * w[0..15]  (w must be wave-uniform -> s_load + v_fma v,s,v)
__device__ __forceinline__ void fma16(float* h, float a, const float* __restrict__ w) {
    #pragma unroll
    for (int j = 0; j < 16; ++j) h[j] = fmaf(a, w[j], h[j]);
}

// ---------------------------------------------------------------- degree count
__global__ __launch_bounds__(256) void deg_kernel(
    const int* __restrict__ ei, int* __restrict__ deg)
{
    int e = blockIdx.x * 256 + threadIdx.x;
    if (e >= E) return;
    atomicAdd(&deg[ei[e]], 1);
}

// ---------------------------------------------------------------- scan (3-kernel hierarchical)
__global__ __launch_bounds__(256) void scanA(
    const int* __restrict__ deg, int* __restrict__ bsum)
{
    __shared__ int sd[256];
    int t = threadIdx.x;
    int n = blockIdx.x * 256 + t;
    sd[t] = (n < N) ? deg[n] : 0;
    __syncthreads();
    #pragma unroll
    for (int s = 128; s > 0; s >>= 1) {
        if (t < s) sd[t] += sd[t + s];
        __syncthreads();
    }
    if (t == 0) bsum[blockIdx.x] = sd[0];
}

__global__ __launch_bounds__(512) void scanB(int* __restrict__ bsum)
{
    __shared__ int sd[512];
    int t = threadIdx.x;
    sd[t] = (t < NB) ? bsum[t] : 0;
    __syncthreads();
    #pragma unroll
    for (int off = 1; off < 512; off <<= 1) {
        int v = (t >= off) ? sd[t - off] : 0;
        __syncthreads();
        sd[t] += v;
        __syncthreads();
    }
    if (t < NB) bsum[t] = (t == 0) ? 0 : sd[t - 1];   // exclusive
}

__global__ __launch_bounds__(256) void scanC(
    const int* __restrict__ deg, const int* __restrict__ bsum,
    int* __restrict__ start)
{
    __shared__ int sd[256];
    int t = threadIdx.x;
    int n = blockIdx.x * 256 + t;
    int v = (n < N) ? deg[n] : 0;
    sd[t] = v;
    __syncthreads();
    #pragma unroll
    for (int off = 1; off < 256; off <<= 1) {
        int w = (t >= off) ? sd[t - off] : 0;
        __syncthreads();
        sd[t] += w;
        __syncthreads();
    }
    if (n < N) start[n] = bsum[blockIdx.x] + sd[t] - v;  // exclusive
}

// ---------------------------------------------------------------- CSR fill
__global__ __launch_bounds__(256) void fill_kernel(
    const int* __restrict__ ei, const float* __restrict__ pos,
    const int* __restrict__ start, int* __restrict__ cursor,
    int* __restrict__ csr_col, float* __restrict__ csr_dist)
{
    int e = blockIdx.x * 256 + threadIdx.x;
    if (e >= E) return;
    int r = ei[e];
    int c = ei[E + e];
    float2 pr = reinterpret_cast<const float2*>(pos)[r];
    float2 pc = reinterpret_cast<const float2*>(pos)[c];
    float dx = pr.x - pc.x, dy = pr.y - pc.y;
    float d = sqrtf(dx * dx + dy * dy);   // pos-mean cancels
    int k = atomicAdd(&cursor[r], 1);
    int s = start[r] + k;
    csr_col[s] = c;
    csr_dist[s] = d;
}

// ---------------------------------------------------------------- node embed
__global__ __launch_bounds__(256) void node_embed_kernel(
    const float* __restrict__ u, const float* __restrict__ v,
    const float* __restrict__ bnorm, const float* __restrict__ yf,
    const float* __restrict__ Wn1, const float* __restrict__ bn1,
    const float* __restrict__ Wn2, const float* __restrict__ bn2,
    float* __restrict__ x)
{
    int n = blockIdx.x * 256 + threadIdx.x;
    if (n >= N) return;

    float f[10];
    float4 uu = reinterpret_cast<const float4*>(u)[n];
    f[0] = uu.x; f[1] = uu.y; f[2] = uu.z; f[3] = uu.w;
    float4 v0 = reinterpret_cast<const float4*>(v)[2 * n];
    float4 v1 = reinterpret_cast<const float4*>(v)[2 * n + 1];
    f[4] = sqrtf(v0.x * v0.x + v0.y * v0.y);
    f[5] = sqrtf(v0.z * v0.z + v0.w * v0.w);
    f[6] = sqrtf(v1.x * v1.x + v1.y * v1.y);
    f[7] = sqrtf(v1.z * v1.z + v1.w * v1.w);
    float2 bb = reinterpret_cast<const float2*>(bnorm)[n];
    f[8] = sqrtf(bb.x * bb.x + bb.y * bb.y);
    float2 yy = reinterpret_cast<const float2*>(yf)[n];
    f[9] = sqrtf(yy.x * yy.x + yy.y * yy.y);

    float h[64];
    #pragma unroll
    for (int j = 0; j < 64; ++j) h[j] = bn1[j];
    #pragma unroll
    for (int i = 0; i < 10; ++i) {
        float t = f[i];
        #pragma unroll
        for (int j = 0; j < 64; ++j) h[j] = fmaf(t, Wn1[i * 64 + j], h[j]);
    }
    #pragma unroll
    for (int j = 0; j < 64; ++j) h[j] = silu_f(h[j]);

    float o[32];
    #pragma unroll
    for (int j = 0; j < 32; ++j) o[j] = bn2[j];
    #pragma unroll
    for (int i = 0; i < 64; ++i) {
        float t = h[i];
        #pragma unroll
        for (int j = 0; j < 32; ++j) o[j] = fmaf(t, Wn2[i * 32 + j], o[j]);
    }
    float4* xo = reinterpret_cast<float4*>(x + (size_t)n * 32);
    #pragma unroll
    for (int i = 0; i < 8; ++i)
        xo[i] = make_float4(o[4 * i], o[4 * i + 1], o[4 * i + 2], o[4 * i + 3]);
}

// ---------------------------------------------------------------- fused layer (4 lanes per node)
// wave w (0..3): ph = w&1 (output half; forced into SGPR via readfirstlane so
//                weight addresses stay scalar -> s_load)
//                nodes nl = (w>>1)*32 + (lane>>1), pe = lane&1 (edge half)
__global__ __launch_bounds__(256) void layer_kernel(
    const int* __restrict__ deg, const int* __restrict__ start,
    const int* __restrict__ csr_col, const float* __restrict__ csr_dist,
    const float* __restrict__ x_in, float* __restrict__ x_out,
    const float* __restrict__ W1, const float* __restrict__ b1,
    const float* __restrict__ W2, const float* __restrict__ b2,
    const float* __restrict__ Wu1, const float* __restrict__ bu1,
    const float* __restrict__ Wu2, const float* __restrict__ bu2)
{
    __shared__ float exA[64][33];   // padded: bank = (nl + j) % 32, conflict-free
    __shared__ float exB[64][33];

    int t = threadIdx.x;
    int w = t >> 6;
    int lane = t & 63;
    // ph is wave-uniform; readfirstlane forces it scalar so ALL weight
    // addressing below stays in SGPRs (s_load + v_fma v,s,v).
    int jo  = __builtin_amdgcn_readfirstlane((w & 1) * 16);
    int joo = jo ^ 16;
    int nl = (w >> 1) * 32 + (lane >> 1);
    int pe = lane & 1;
    int n = blockIdx.x * 64 + nl;
    bool valid = (n < N);
    size_t ns = valid ? (size_t)n : 0;

    const float4* xi4 = reinterpret_cast<const float4*>(x_in + ns * 32);

    // ---- hbase[16] = b1h + W1[0:32, half].x[n]
    float hb[16];
    #pragma unroll
    for (int j = 0; j < 16; ++j) hb[j] = b1[jo + j];
    {
        const float* wb = W1 + jo;
        #pragma unroll 1
        for (int i = 0; i < 8; ++i) {
            float4 q = xi4[i];
            const float* wr = wb + i * 4 * 32;
            fma16(hb, q.x, wr);
            fma16(hb, q.y, wr + 32);
            fma16(hb, q.z, wr + 64);
            fma16(hb, q.w, wr + 96);
        }
    }

    // ---- edge loop (pe-strided)
    float sh[16];
    #pragma unroll
    for (int j = 0; j < 16; ++j) sh[j] = 0.0f;

    int s0 = valid ? start[n] : 0;
    int dg = valid ? deg[n] : 0;
    const float* W1c = W1 + 32 * 32 + jo;   // x[col] rows
    const float* W1r = W1 + 64 * 32 + jo;   // rbf rows
    #pragma unroll 1
    for (int s = s0 + pe; s < s0 + dg; s += 2) {
        int c = csr_col[s];
        float d = csr_dist[s];
        const float4* xc4 = reinterpret_cast<const float4*>(x_in + (size_t)c * 32);

        float h[16];
        #pragma unroll
        for (int j = 0; j < 16; ++j) h[j] = hb[j];

        #pragma unroll 1
        for (int ch = 0; ch < 4; ++ch) {
            float4 a0 = xc4[ch * 2 + 0];
            float4 a1 = xc4[ch * 2 + 1];
            const float* wr = W1c + ch * 8 * 32;
            fma16(h, a0.x, wr);           fma16(h, a0.y, wr + 32);
            fma16(h, a0.z, wr + 64);      fma16(h, a0.w, wr + 96);
            fma16(h, a1.x, wr + 128);     fma16(h, a1.y, wr + 160);
            fma16(h, a1.z, wr + 192);     fma16(h, a1.w, wr + 224);
        }

        // rbf(d): sqrt(2)*sin(k*pi*d)/(d+eps), k=1..16 via sin recurrence
        float s1 = __sinf(PI_F * d);
        float c1 = __cosf(PI_F * d);
        float inv = SQRT2_F / (d + 1e-8f);
        float tc = 2.0f * c1;
        float sk = s1, skm = 0.0f;
        #pragma unroll
        for (int k = 0; k < 16; ++k) {
            fma16(h, sk * inv, W1r + k * 32);
            float s2 = tc * sk - skm; skm = sk; sk = s2;
        }

        #pragma unroll
        for (int j = 0; j < 16; ++j) sh[j] += silu_f(h[j]);
    }

    // ---- merge pe halves (adjacent lanes)
    #pragma unroll
    for (int j = 0; j < 16; ++j) sh[j] += __shfl_xor(sh[j], 1, 64);

    // ---- agg = (sh @ W2 + deg*b2) / deg : partials over own sh rows for both halves
    float pa_own[16], pa_oth[16];
    #pragma unroll
    for (int j = 0; j < 16; ++j) { pa_own[j] = 0.0f; pa_oth[j] = 0.0f; }
    #pragma unroll 1
    for (int kk = 0; kk < 16; ++kk) {
        float sv = sh[kk];
        const float* wr = W2 + (jo + kk) * 32;
        fma16(pa_own, sv, wr + jo);
        fma16(pa_oth, sv, wr + joo);
    }
    if (pe == 0) {
        #pragma unroll
        for (int j = 0; j < 16; ++j) exA[nl][joo + j] = pa_oth[j];
    }
    __syncthreads();

    float fdg = (float)dg;
    float ivd = 1.0f / fmaxf(fdg, 1.0f);
    float ag[16];
    #pragma unroll
    for (int j = 0; j < 16; ++j)
        ag[j] = (pa_own[j] + exA[nl][jo + j] + fdg * b2[jo + j]) * ivd;

    if (pe == 0) {
        #pragma unroll
        for (int j = 0; j < 16; ++j) exB[nl][jo + j] = ag[j];
    }
    __syncthreads();
    float ago[16];
    #pragma unroll
    for (int j = 0; j < 16; ++j) ago[j] = exB[nl][joo + j];

    // ---- node update: hu = silu(bu1h + Wu1.[x(32); agg(32)] half)
    float hu[16];
    #pragma unroll
    for (int j = 0; j < 16; ++j) hu[j] = bu1[jo + j];
    {
        const float* wb = Wu1 + jo;
        #pragma unroll 1
        for (int i = 0; i < 8; ++i) {
            float4 q = xi4[i];
            const float* wr = wb + i * 4 * 32;
            fma16(hu, q.x, wr);
            fma16(hu, q.y, wr + 32);
            fma16(hu, q.z, wr + 64);
            fma16(hu, q.w, wr + 96);
        }
        const float* wro = Wu1 + (32 + jo) * 32 + jo;   // own agg rows
        const float* wrx = Wu1 + (32 + joo) * 32 + jo;  // other agg rows
        #pragma unroll 1
        for (int kk = 0; kk < 16; ++kk) {
            fma16(hu, ag[kk],  wro + kk * 32);
            fma16(hu, ago[kk], wrx + kk * 32);
        }
    }
    #pragma unroll
    for (int j = 0; j < 16; ++j) hu[j] = silu_f(hu[j]);

    __syncthreads();   // WAR on exA
    if (pe == 0) {
        #pragma unroll
        for (int j = 0; j < 16; ++j) exA[nl][jo + j] = hu[j];
    }
    __syncthreads();

    // ---- o = bu2h + Wu2.hu(32) ; x_out = x + o
    float o[16];
    #pragma unroll
    for (int j = 0; j < 16; ++j) o[j] = bu2[jo + j];
    {
        const float* wro = Wu2 + jo * 32 + jo;
        #pragma unroll 1
        for (int kk = 0; kk < 16; ++kk)
            fma16(o, hu[kk], wro + kk * 32);
        const float* wrx = Wu2 + joo * 32 + jo;
        #pragma unroll 1
        for (int kk = 0; kk < 16; ++kk)
            fma16(o, exA[nl][joo + kk], wrx + kk * 32);
    }

    if (valid) {
        // lane writes 8 floats: dims [jo + pe*8, +8)
        float ov[8];
        #pragma unroll
        for (int j = 0; j < 8; ++j) ov[j] = pe ? o[8 + j] : o[j];
        const float4* xi = reinterpret_cast<const float4*>(x_in + (size_t)n * 32 + jo + pe * 8);
        float4* xo = reinterpret_cast<float4*>(x_out + (size_t)n * 32 + jo + pe * 8);
        float4 r0 = xi[0], r1 = xi[1];
        xo[0] = make_float4(r0.x + ov[0], r0.y + ov[1], r0.z + ov[2], r0.w + ov[3]);
        xo[1] = make_float4(r1.x + ov[4], r1.y + ov[5], r1.z + ov[6], r1.w + ov[7]);
    }
}

// ---------------------------------------------------------------- LN + heads
__global__ __launch_bounds__(256) void final_kernel(
    const float* __restrict__ x, const float* __restrict__ u,
    const float* __restrict__ v,
    const float* __restrict__ ln_g, const float* __restrict__ ln_b,
    const float* __restrict__ Wr1, const float* __restrict__ br1,
    const float* __restrict__ Wr2, const float* __restrict__ br2,
    const float* __restrict__ Ws1, const float* __restrict__ bs1,
    const float* __restrict__ Ws2, const float* __restrict__ bs2,
    float* __restrict__ out)
{
    int n = blockIdx.x * 256 + threadIdx.x;
    if (n >= N) return;

    float a[32];
    const float4* x4 = reinterpret_cast<const float4*>(x + (size_t)n * 32);
    #pragma unroll
    for (int i = 0; i < 8; ++i) {
        float4 t = x4[i];
        a[4 * i] = t.x; a[4 * i + 1] = t.y; a[4 * i + 2] = t.z; a[4 * i + 3] = t.w;
    }
    float mu = 0.0f;
    #pragma unroll
    for (int i = 0; i < 32; ++i) mu += a[i];
    mu *= (1.0f / 32.0f);
    float var = 0.0f;
    #pragma unroll
    for (int i = 0; i < 32; ++i) { float dlt = a[i] - mu; var += dlt * dlt; }
    var *= (1.0f / 32.0f);
    float rs = rsqrtf(var + 1e-5f);
    #pragma unroll
    for (int i = 0; i < 32; ++i) a[i] = (a[i] - mu) * rs * ln_g[i] + ln_b[i];

    float o0 = br2[0], o1 = br2[1], o2 = bs2[0];
    #pragma unroll 1
    for (int j = 0; j < 96; ++j) {
        float hr = br1[j];
        float hs = bs1[j];
        #pragma unroll
        for (int i = 0; i < 32; ++i) {
            hr = fmaf(a[i], Wr1[i * 96 + j], hr);
            hs = fmaf(a[i], Ws1[i * 96 + j], hs);
        }
        hr = silu_f(hr);
        hs = silu_f(hs);
        o0 = fmaf(hr, Wr2[2 * j], o0);
        o1 = fmaf(hr, Wr2[2 * j + 1], o1);
        o2 = fmaf(hs, Ws2[j], o2);
    }
    out[n] = u[n * 4 + 3] + o2;
    out[N + 2 * n]     = o0 + v[n * 8 + 6];
    out[N + 2 * n + 1] = o1 + v[n * 8 + 7];
}

} // anonymous namespace

extern "C" void kernel_launch(void* const* d_in, const int* in_sizes, int n_in,
                              void* d_out, int out_size, void* d_ws, size_t ws_size,
                              hipStream_t stream)
{
    const float* u    = (const float*)d_in[0];
    const float* v    = (const float*)d_in[1];
    const float* bno  = (const float*)d_in[2];
    const float* yf   = (const float*)d_in[4];
    const float* pos  = (const float*)d_in[5];
    const int*   ei   = (const int*)d_in[6];
    const float* Wn1  = (const float*)d_in[7];
    const float* bn1  = (const float*)d_in[8];
    const float* Wn2  = (const float*)d_in[9];
    const float* bn2  = (const float*)d_in[10];
    const float* We1  = (const float*)d_in[11];
    const float* be1  = (const float*)d_in[12];
    const float* We2  = (const float*)d_in[13];
    const float* be2  = (const float*)d_in[14];
    const float* Wu1  = (const float*)d_in[15];
    const float* bu1  = (const float*)d_in[16];
    const float* Wu2  = (const float*)d_in[17];
    const float* bu2  = (const float*)d_in[18];
    const float* ln_g = (const float*)d_in[19];
    const float* ln_b = (const float*)d_in[20];
    const float* Wr1  = (const float*)d_in[21];
    const float* br1  = (const float*)d_in[22];
    const float* Wr2  = (const float*)d_in[23];
    const float* br2  = (const float*)d_in[24];
    const float* Ws1  = (const float*)d_in[25];
    const float* bs1  = (const float*)d_in[26];
    const float* Ws2  = (const float*)d_in[27];
    const float* bs2  = (const float*)d_in[28];
    float* out = (float*)d_out;

    // workspace layout
    int*   deg      = (int*)d_ws;                    // N
    int*   cursor   = deg + N;                       // N
    int*   start    = cursor + N;                    // N
    int*   bsum     = start + N;                     // 512
    int*   csr_col  = bsum + 512;                    // E
    float* csr_dist = (float*)(csr_col + E);         // E
    float* x0       = csr_dist + E;                  // N*S
    float* x1       = x0 + (size_t)N * S;            // N*S

    const int egrid = (E + 255) / 256;

    hipMemsetAsync(deg, 0, 2 * N * sizeof(int), stream);   // deg + cursor
    deg_kernel<<<egrid, 256, 0, stream>>>(ei, deg);
    scanA<<<NB, 256, 0, stream>>>(deg, bsum);
    scanB<<<1, 512, 0, stream>>>(bsum);
    scanC<<<NB, 256, 0, stream>>>(deg, bsum, start);
    fill_kernel<<<egrid, 256, 0, stream>>>(ei, pos, start, cursor, csr_col, csr_dist);

    node_embed_kernel<<<NB, 256, 0, stream>>>(u, v, bno, yf, Wn1, bn1, Wn2, bn2, x0);

    float* xin = x0;
    float* xout = x1;
    for (int l = 0; l < L; ++l) {
        layer_kernel<<<LB, 256, 0, stream>>>(
            deg, start, csr_col, csr_dist, xin, xout,
            We1 + (size_t)l * 80 * 32, be1 + (size_t)l * 32,
            We2 + (size_t)l * 32 * 32, be2 + (size_t)l * 32,
            Wu1 + (size_t)l * 64 * 32, bu1 + (size_t)l * 32,
            Wu2 + (size_t)l * 32 * 32, bu2 + (size_t)l * 32);
        float* tmp = xin; xin = xout; xout = tmp;
    }

    final_kernel<<<NB, 256, 0, stream>>>(xin, u, v, ln_g, ln_b,
                                         Wr1, br1, Wr2, br2,
                                         Ws1, bs1, Ws2, bs2, out);
}

// Round 5
// 1036.944 us; speedup vs baseline: 13.7776x; 2.4720x over previous
//
#include <hip/hip_runtime.h>
#include <cmath>

namespace {

constexpr int N = 100000;
constexpr int E = 1600000;
constexpr int S = 32;           // hidden
constexpr int L = 5;            // layers
constexpr int NB = (N + 255) / 256;   // node-per-thread kernels
constexpr float PI_F    = 3.14159265358979323846f;
constexpr float SQRT2_F = 1.41421356237309515f;

typedef __attribute__((ext_vector_type(8))) short short8;   // 8 x bf16
typedef __attribute__((ext_vector_type(4))) float f32x4;

__device__ __forceinline__ float silu_f(float x) {
    return x / (1.0f + __expf(-x));
}

// float -> bf16 bits, round-to-nearest-even
__device__ __forceinline__ unsigned short f2bf(float f) {
    unsigned int u = __float_as_uint(f);
    u = (u + 0x7FFFu + ((u >> 16) & 1u)) >> 16;
    return (unsigned short)u;
}

// ---------------------------------------------------------------- degree count
__global__ __launch_bounds__(256) void deg_kernel(
    const int* __restrict__ ei, int* __restrict__ deg)
{
    int e = blockIdx.x * 256 + threadIdx.x;
    if (e >= E) return;
    atomicAdd(&deg[ei[e]], 1);
}

// ---------------------------------------------------------------- scan (3-kernel hierarchical)
__global__ __launch_bounds__(256) void scanA(
    const int* __restrict__ deg, int* __restrict__ bsum)
{
    __shared__ int sd[256];
    int t = threadIdx.x;
    int n = blockIdx.x * 256 + t;
    sd[t] = (n < N) ? deg[n] : 0;
    __syncthreads();
    #pragma unroll
    for (int s = 128; s > 0; s >>= 1) {
        if (t < s) sd[t] += sd[t + s];
        __syncthreads();
    }
    if (t == 0) bsum[blockIdx.x] = sd[0];
}

__global__ __launch_bounds__(512) void scanB(int* __restrict__ bsum)
{
    __shared__ int sd[512];
    int t = threadIdx.x;
    sd[t] = (t < NB) ? bsum[t] : 0;
    __syncthreads();
    #pragma unroll
    for (int off = 1; off < 512; off <<= 1) {
        int v = (t >= off) ? sd[t - off] : 0;
        __syncthreads();
        sd[t] += v;
        __syncthreads();
    }
    if (t < NB) bsum[t] = (t == 0) ? 0 : sd[t - 1];   // exclusive
}

__global__ __launch_bounds__(256) void scanC(
    const int* __restrict__ deg, const int* __restrict__ bsum,
    int* __restrict__ start)
{
    __shared__ int sd[256];
    int t = threadIdx.x;
    int n = blockIdx.x * 256 + t;
    int v = (n < N) ? deg[n] : 0;
    sd[t] = v;
    __syncthreads();
    #pragma unroll
    for (int off = 1; off < 256; off <<= 1) {
        int w = (t >= off) ? sd[t - off] : 0;
        __syncthreads();
        sd[t] += w;
        __syncthreads();
    }
    if (n < N) start[n] = bsum[blockIdx.x] + sd[t] - v;  // exclusive
}

// ---------------------------------------------------------------- CSR fill
__global__ __launch_bounds__(256) void fill_kernel(
    const int* __restrict__ ei, const float* __restrict__ pos,
    const int* __restrict__ start, int* __restrict__ cursor,
    int* __restrict__ csr_col, float* __restrict__ csr_dist)
{
    int e = blockIdx.x * 256 + threadIdx.x;
    if (e >= E) return;
    int r = ei[e];
    int c = ei[E + e];
    float2 pr = reinterpret_cast<const float2*>(pos)[r];
    float2 pc = reinterpret_cast<const float2*>(pos)[c];
    float dx = pr.x - pc.x, dy = pr.y - pc.y;
    float d = sqrtf(dx * dx + dy * dy);   // pos-mean cancels
    int k = atomicAdd(&cursor[r], 1);
    int s = start[r] + k;
    csr_col[s] = c;
    csr_dist[s] = d;
}

// ---------------------------------------------------------------- bf16 weight prep
// wt[l][n][k] = bf16(We1[l][k][n]) for k<80 else 0 ; [32 n][96 k] per layer
__global__ __launch_bounds__(256) void prep_wt_kernel(
    const float* __restrict__ We1, short* __restrict__ wt)
{
    int idx = blockIdx.x * 256 + threadIdx.x;
    if (idx >= 5 * 32 * 96) return;
    int l = idx / (32 * 96);
    int r = idx % (32 * 96);
    int n = r / 96;
    int k = r % 96;
    float v = (k < 80) ? We1[((size_t)l * 80 + k) * 32 + n] : 0.0f;
    wt[idx] = (short)f2bf(v);
}

// ---------------------------------------------------------------- node embed (writes fp32 x + bf16 xb)
__global__ __launch_bounds__(256) void node_embed_kernel(
    const float* __restrict__ u, const float* __restrict__ v,
    const float* __restrict__ bnorm, const float* __restrict__ yf,
    const float* __restrict__ Wn1, const float* __restrict__ bn1,
    const float* __restrict__ Wn2, const float* __restrict__ bn2,
    float* __restrict__ x, unsigned short* __restrict__ xb)
{
    int n = blockIdx.x * 256 + threadIdx.x;
    if (n >= N) return;

    float f[10];
    float4 uu = reinterpret_cast<const float4*>(u)[n];
    f[0] = uu.x; f[1] = uu.y; f[2] = uu.z; f[3] = uu.w;
    float4 v0 = reinterpret_cast<const float4*>(v)[2 * n];
    float4 v1 = reinterpret_cast<const float4*>(v)[2 * n + 1];
    f[4] = sqrtf(v0.x * v0.x + v0.y * v0.y);
    f[5] = sqrtf(v0.z * v0.z + v0.w * v0.w);
    f[6] = sqrtf(v1.x * v1.x + v1.y * v1.y);
    f[7] = sqrtf(v1.z * v1.z + v1.w * v1.w);
    float2 bb = reinterpret_cast<const float2*>(bnorm)[n];
    f[8] = sqrtf(bb.x * bb.x + bb.y * bb.y);
    float2 yy = reinterpret_cast<const float2*>(yf)[n];
    f[9] = sqrtf(yy.x * yy.x + yy.y * yy.y);

    float h[64];
    #pragma unroll
    for (int j = 0; j < 64; ++j) h[j] = bn1[j];
    #pragma unroll
    for (int i = 0; i < 10; ++i) {
        float t = f[i];
        #pragma unroll
        for (int j = 0; j < 64; ++j) h[j] = fmaf(t, Wn1[i * 64 + j], h[j]);
    }
    #pragma unroll
    for (int j = 0; j < 64; ++j) h[j] = silu_f(h[j]);

    float o[32];
    #pragma unroll
    for (int j = 0; j < 32; ++j) o[j] = bn2[j];
    #pragma unroll
    for (int i = 0; i < 64; ++i) {
        float t = h[i];
        #pragma unroll
        for (int j = 0; j < 32; ++j) o[j] = fmaf(t, Wn2[i * 32 + j], o[j]);
    }
    float4* xo = reinterpret_cast<float4*>(x + (size_t)n * 32);
    #pragma unroll
    for (int i = 0; i < 8; ++i)
        xo[i] = make_float4(o[4 * i], o[4 * i + 1], o[4 * i + 2], o[4 * i + 3]);

    unsigned int* xbu = reinterpret_cast<unsigned int*>(xb) + (size_t)n * 16;
    #pragma unroll
    for (int i = 0; i < 16; ++i)
        xbu[i] = (unsigned int)f2bf(o[2 * i]) | ((unsigned int)f2bf(o[2 * i + 1]) << 16);
}

// ---------------------------------------------------------------- fused layer, MFMA edge phase
// One wave per node. Edge tile: M=16 edges, K=96 = [x_row(32) | x_col(32) | rbf16+pad],
// N=32 outputs as 2 n-halves. 6 MFMA per tile. Row-masked silu reduction -> sh[32].
// Node phase: lane-split fp32 vector matmuls through wave-private LDS.
__global__ __launch_bounds__(256) void layer_kernel(
    const int* __restrict__ deg, const int* __restrict__ start,
    const int* __restrict__ csr_col, const float* __restrict__ csr_dist,
    const float* __restrict__ x_in, const unsigned short* __restrict__ xb_in,
    float* __restrict__ x_out, unsigned short* __restrict__ xb_out,
    const short* __restrict__ wt1,   // [32][96] bf16, this layer
    const float* __restrict__ b1, const float* __restrict__ W2,
    const float* __restrict__ b2,
    const float* __restrict__ Wu1, const float* __restrict__ bu1,
    const float* __restrict__ Wu2, const float* __restrict__ bu2)
{
    __shared__ float lsh[4][32];   // per-wave sh[32]
    __shared__ float lxa[4][64];   // per-wave [x(32) | ag(32)]
    __shared__ float lhu[4][32];   // per-wave hu[32]

    int t = threadIdx.x;
    int w = t >> 6;
    int lane = t & 63;
    int quad = lane >> 4;
    int ml = lane & 15;
    int n = __builtin_amdgcn_readfirstlane(blockIdx.x * 4 + w);   // wave-uniform node

    int s0 = start[n];
    int dg = deg[n];

    // ---- preload x[n] into LDS (fp32, for node phase)
    int j32 = lane & 31;
    int half = lane >> 5;
    if (half == 0) lxa[w][j32] = x_in[(size_t)n * 32 + j32];

    // ---- B fragments: wt1[n=ml+16*h][k = ks*32 + quad*8 + 0..7], 16B each
    const short8* wp = reinterpret_cast<const short8*>(wt1);
    short8 B00 = wp[(ml     ) * 12 + 0 * 4 + quad];
    short8 B01 = wp[(ml     ) * 12 + 1 * 4 + quad];
    short8 B02 = wp[(ml     ) * 12 + 2 * 4 + quad];
    short8 B10 = wp[(ml + 16) * 12 + 0 * 4 + quad];
    short8 B11 = wp[(ml + 16) * 12 + 1 * 4 + quad];
    short8 B12 = wp[(ml + 16) * 12 + 2 * 4 + quad];

    // ---- A0 fragment: x_row (same for every edge row m)
    const short8* xbp = reinterpret_cast<const short8*>(xb_in);
    short8 A0 = xbp[(size_t)n * 4 + quad];

    float b1j0 = b1[ml];
    float b1j1 = b1[ml + 16];

    float colp0 = 0.0f, colp1 = 0.0f;
    int ntile = (dg + 15) >> 4;

    #pragma unroll 1
    for (int tile = 0; tile < ntile; ++tile) {
        int slot = s0 + tile * 16 + ml;
        slot = min(slot, E - 1);                 // clamp (masked below)
        int c = csr_col[slot];
        float d = csr_dist[slot];

        short8 A1 = xbp[(size_t)c * 4 + quad];   // x_col fragment

        // rbf fragment: k_local = quad*8 + j -> freq (k_local+1)*pi*d ; quads 2,3 = pad
        float th = PI_F * d;
        float s1 = __sinf(th);
        float c1 = __cosf(th);
        float inv = SQRT2_F / (d + 1e-8f);
        float s2 = 2.0f * s1 * c1,  c2 = fmaf(-2.0f * s1, s1, 1.0f);
        float s4 = 2.0f * s2 * c2,  c4 = fmaf(-2.0f * s2, s2, 1.0f);
        float s8 = 2.0f * s4 * c4,  c8 = fmaf(-2.0f * s4, s4, 1.0f);
        float s16 = 2.0f * s8 * c8, c16 = fmaf(-2.0f * s8, s8, 1.0f);
        float s24 = s16 * c8 + c16 * s8;
        float c24 = c16 * c8 - s16 * s8;
        float sA = (quad == 0) ? 0.0f : (quad == 1) ? s8 : (quad == 2) ? s16 : s24;
        float cA = (quad == 0) ? 1.0f : (quad == 1) ? c8 : (quad == 2) ? c16 : c24;
        bool rq = (quad < 2);
        short8 A2;
        #pragma unroll
        for (int j = 0; j < 8; ++j) {
            float sn = sA * c1 + cA * s1;
            float cn = cA * c1 - sA * s1;
            float rv = rq ? sn * inv : 0.0f;
            A2[j] = (short)f2bf(rv);
            sA = sn; cA = cn;
        }

        f32x4 acc0 = {0.0f, 0.0f, 0.0f, 0.0f};
        f32x4 acc1 = {0.0f, 0.0f, 0.0f, 0.0f};
        acc0 = __builtin_amdgcn_mfma_f32_16x16x32_bf16(A0, B00, acc0, 0, 0, 0);
        acc0 = __builtin_amdgcn_mfma_f32_16x16x32_bf16(A1, B01, acc0, 0, 0, 0);
        acc0 = __builtin_amdgcn_mfma_f32_16x16x32_bf16(A2, B02, acc0, 0, 0, 0);
        acc1 = __builtin_amdgcn_mfma_f32_16x16x32_bf16(A0, B10, acc1, 0, 0, 0);
        acc1 = __builtin_amdgcn_mfma_f32_16x16x32_bf16(A1, B11, acc1, 0, 0, 0);
        acc1 = __builtin_amdgcn_mfma_f32_16x16x32_bf16(A2, B12, acc1, 0, 0, 0);

        // epilogue: C row = quad*4 + r (edge), col = ml (+16). bias+silu, mask, reduce
        int rowbase = tile * 16 + quad * 4;
        #pragma unroll
        for (int r = 0; r < 4; ++r) {
            bool vld = (rowbase + r) < dg;
            float h0 = acc0[r] + b1j0;
            float h1 = acc1[r] + b1j1;
            colp0 += vld ? silu_f(h0) : 0.0f;
            colp1 += vld ? silu_f(h1) : 0.0f;
        }
    }

    // reduce over quads: lanes ml, ml+16, ml+32, ml+48 hold partial row-group sums
    colp0 += __shfl_xor(colp0, 16, 64);
    colp0 += __shfl_xor(colp0, 32, 64);
    colp1 += __shfl_xor(colp1, 16, 64);
    colp1 += __shfl_xor(colp1, 32, 64);
    if (quad == 0) {
        lsh[w][ml] = colp0;
        lsh[w][ml + 16] = colp1;
    }
    __syncthreads();

    // ---- ag = (sh @ W2 + dg*b2) / max(dg,1)   (lane pair j, j+32 split k)
    float fdg = (float)dg;
    float ivd = 1.0f / fmaxf(fdg, 1.0f);
    float s = 0.0f;
    #pragma unroll
    for (int k16 = 0; k16 < 16; ++k16) {
        int k = half * 16 + k16;
        s = fmaf(lsh[w][k], W2[k * 32 + j32], s);
    }
    s += __shfl_xor(s, 32, 64);
    float ag = (s + fdg * b2[j32]) * ivd;
    if (half == 0) lxa[w][32 + j32] = ag;
    __syncthreads();

    // ---- hu = silu(bu1 + [x; ag] @ Wu1)   (k split: half0 -> x rows, half1 -> ag rows)
    float s2v = 0.0f;
    #pragma unroll
    for (int k = 0; k < 32; ++k) {
        int kk = half * 32 + k;
        s2v = fmaf(lxa[w][kk], Wu1[kk * 32 + j32], s2v);
    }
    s2v += __shfl_xor(s2v, 32, 64);
    float hu = silu_f(s2v + bu1[j32]);
    if (half == 0) lhu[w][j32] = hu;
    __syncthreads();

    // ---- o = bu2 + hu @ Wu2 ; x_out = x + o
    float s3 = 0.0f;
    #pragma unroll
    for (int k16 = 0; k16 < 16; ++k16) {
        int kk = half * 16 + k16;
        s3 = fmaf(lhu[w][kk], Wu2[kk * 32 + j32], s3);
    }
    s3 += __shfl_xor(s3, 32, 64);
    if (half == 0) {
        float xo = lxa[w][j32] + s3 + bu2[j32];
        x_out[(size_t)n * 32 + j32] = xo;
        xb_out[(size_t)n * 32 + j32] = f2bf(xo);
    }
}

// ---------------------------------------------------------------- LN + heads
__global__ __launch_bounds__(256) void final_kernel(
    const float* __restrict__ x, const float* __restrict__ u,
    const float* __restrict__ v,
    const float* __restrict__ ln_g, const float* __restrict__ ln_b,
    const float* __restrict__ Wr1, const float* __restrict__ br1,
    const float* __restrict__ Wr2, const float* __restrict__ br2,
    const float* __restrict__ Ws1, const float* __restrict__ bs1,
    const float* __restrict__ Ws2, const float* __restrict__ bs2,
    float* __restrict__ out)
{
    int n = blockIdx.x * 256 + threadIdx.x;
    if (n >= N) return;

    float a[32];
    const float4* x4 = reinterpret_cast<const float4*>(x + (size_t)n * 32);
    #pragma unroll
    for (int i = 0; i < 8; ++i) {
        float4 t = x4[i];
        a[4 * i] = t.x; a[4 * i + 1] = t.y; a[4 * i + 2] = t.z; a[4 * i + 3] = t.w;
    }
    float mu = 0.0f;
    #pragma unroll
    for (int i = 0; i < 32; ++i) mu += a[i];
    mu *= (1.0f / 32.0f);
    float var = 0.0f;
    #pragma unroll
    for (int i = 0; i < 32; ++i) { float dlt = a[i] - mu; var += dlt * dlt; }
    var *= (1.0f / 32.0f);
    float rs = rsqrtf(var + 1e-5f);
    #pragma unroll
    for (int i = 0; i < 32; ++i) a[i] = (a[i] - mu) * rs * ln_g[i] + ln_b[i];

    float o0 = br2[0], o1 = br2[1], o2 = bs2[0];
    #pragma unroll 1
    for (int j = 0; j < 96; ++j) {
        float hr = br1[j];
        float hs = bs1[j];
        #pragma unroll
        for (int i = 0; i < 32; ++i) {
            hr = fmaf(a[i], Wr1[i * 96 + j], hr);
            hs = fmaf(a[i], Ws1[i * 96 + j], hs);
        }
        hr = silu_f(hr);
        hs = silu_f(hs);
        o0 = fmaf(hr, Wr2[2 * j], o0);
        o1 = fmaf(hr, Wr2[2 * j + 1], o1);
        o2 = fmaf(hs, Ws2[j], o2);
    }
    out[n] = u[n * 4 + 3] + o2;
    out[N + 2 * n]     = o0 + v[n * 8 + 6];
    out[N + 2 * n + 1] = o1 + v[n * 8 + 7];
}

} // anonymous namespace

extern "C" void kernel_launch(void* const* d_in, const int* in_sizes, int n_in,
                              void* d_out, int out_size, void* d_ws, size_t ws_size,
                              hipStream_t stream)
{
    const float* u    = (const float*)d_in[0];
    const float* v    = (const float*)d_in[1];
    const float* bno  = (const float*)d_in[2];
    const float* yf   = (const float*)d_in[4];
    const float* pos  = (const float*)d_in[5];
    const int*   ei   = (const int*)d_in[6];
    const float* Wn1  = (const float*)d_in[7];
    const float* bn1  = (const float*)d_in[8];
    const float* Wn2  = (const float*)d_in[9];
    const float* bn2  = (const float*)d_in[10];
    const float* We1  = (const float*)d_in[11];
    const float* be1  = (const float*)d_in[12];
    const float* We2  = (const float*)d_in[13];
    const float* be2  = (const float*)d_in[14];
    const float* Wu1  = (const float*)d_in[15];
    const float* bu1  = (const float*)d_in[16];
    const float* Wu2  = (const float*)d_in[17];
    const float* bu2  = (const float*)d_in[18];
    const float* ln_g = (const float*)d_in[19];
    const float* ln_b = (const float*)d_in[20];
    const float* Wr1  = (const float*)d_in[21];
    const float* br1  = (const float*)d_in[22];
    const float* Wr2  = (const float*)d_in[23];
    const float* br2  = (const float*)d_in[24];
    const float* Ws1  = (const float*)d_in[25];
    const float* bs1  = (const float*)d_in[26];
    const float* Ws2  = (const float*)d_in[27];
    const float* bs2  = (const float*)d_in[28];
    float* out = (float*)d_out;

    // workspace layout (16B-aligned sections)
    int*   deg      = (int*)d_ws;                            // N
    int*   cursor   = deg + N;                               // N
    int*   start    = cursor + N;                            // N
    int*   bsum     = start + N;                             // 512
    int*   csr_col  = bsum + 512;                            // E
    float* csr_dist = (float*)(csr_col + E);                 // E
    float* x0       = csr_dist + E;                          // N*32 f32
    float* x1       = x0 + (size_t)N * S;                    // N*32 f32
    unsigned short* xb0 = (unsigned short*)(x1 + (size_t)N * S);   // N*32 bf16
    unsigned short* xb1 = xb0 + (size_t)N * S;               // N*32 bf16
    short* wt       = (short*)(xb1 + (size_t)N * S);         // 5*32*96 bf16

    const int egrid = (E + 255) / 256;

    hipMemsetAsync(deg, 0, 2 * N * sizeof(int), stream);   // deg + cursor
    deg_kernel<<<egrid, 256, 0, stream>>>(ei, deg);
    scanA<<<NB, 256, 0, stream>>>(deg, bsum);
    scanB<<<1, 512, 0, stream>>>(bsum);
    scanC<<<NB, 256, 0, stream>>>(deg, bsum, start);
    fill_kernel<<<egrid, 256, 0, stream>>>(ei, pos, start, cursor, csr_col, csr_dist);
    prep_wt_kernel<<<60, 256, 0, stream>>>(We1, wt);

    node_embed_kernel<<<NB, 256, 0, stream>>>(u, v, bno, yf, Wn1, bn1, Wn2, bn2,
                                              x0, xb0);

    float* xin = x0;  float* xout = x1;
    unsigned short* xbin = xb0;  unsigned short* xbout = xb1;
    for (int l = 0; l < L; ++l) {
        layer_kernel<<<N / 4, 256, 0, stream>>>(
            deg, start, csr_col, csr_dist, xin, xbin, xout, xbout,
            wt + (size_t)l * 32 * 96,
            be1 + (size_t)l * 32,
            We2 + (size_t)l * 32 * 32, be2 + (size_t)l * 32,
            Wu1 + (size_t)l * 64 * 32, bu1 + (size_t)l * 32,
            Wu2 + (size_t)l * 32 * 32, bu2 + (size_t)l * 32);
        float* tf = xin; xin = xout; xout = tf;
        unsigned short* tb = xbin; xbin = xbout; xbout = tb;
    }

    final_kernel<<<NB, 256, 0, stream>>>(xin, u, v, ln_g, ln_b,
                                         Wr1, br1, Wr2, br2,
                                         Ws1, bs1, Ws2, bs2, out);
}

// Round 6
// 1005.870 us; speedup vs baseline: 14.2032x; 1.0309x over previous
//
#include <hip/hip_runtime.h>
#include <cmath>

namespace {

constexpr int N = 100000;
constexpr int E = 1600000;
constexpr int S = 32;           // hidden
constexpr int L = 5;            // layers
constexpr int NB = (N + 255) / 256;   // node-per-thread kernels
constexpr float PI_F    = 3.14159265358979323846f;
constexpr float SQRT2_F = 1.41421356237309515f;

typedef __attribute__((ext_vector_type(8))) short short8;   // 8 x bf16
typedef __attribute__((ext_vector_type(4))) float f32x4;

__device__ __forceinline__ float silu_f(float x) {
    return x / (1.0f + __expf(-x));
}

// float -> bf16 bits, round-to-nearest-even
__device__ __forceinline__ unsigned short f2bf(float f) {
    unsigned int u = __float_as_uint(f);
    u = (u + 0x7FFFu + ((u >> 16) & 1u)) >> 16;
    return (unsigned short)u;
}

// ---------------------------------------------------------------- degree count
__global__ __launch_bounds__(256) void deg_kernel(
    const int* __restrict__ ei, int* __restrict__ deg)
{
    int e = blockIdx.x * 256 + threadIdx.x;
    if (e >= E) return;
    atomicAdd(&deg[ei[e]], 1);
}

// ---------------------------------------------------------------- scan (3-kernel hierarchical)
__global__ __launch_bounds__(256) void scanA(
    const int* __restrict__ deg, int* __restrict__ bsum)
{
    __shared__ int sd[256];
    int t = threadIdx.x;
    int n = blockIdx.x * 256 + t;
    sd[t] = (n < N) ? deg[n] : 0;
    __syncthreads();
    #pragma unroll
    for (int s = 128; s > 0; s >>= 1) {
        if (t < s) sd[t] += sd[t + s];
        __syncthreads();
    }
    if (t == 0) bsum[blockIdx.x] = sd[0];
}

__global__ __launch_bounds__(512) void scanB(int* __restrict__ bsum)
{
    __shared__ int sd[512];
    int t = threadIdx.x;
    sd[t] = (t < NB) ? bsum[t] : 0;
    __syncthreads();
    #pragma unroll
    for (int off = 1; off < 512; off <<= 1) {
        int v = (t >= off) ? sd[t - off] : 0;
        __syncthreads();
        sd[t] += v;
        __syncthreads();
    }
    if (t < NB) bsum[t] = (t == 0) ? 0 : sd[t - 1];   // exclusive
}

__global__ __launch_bounds__(256) void scanC(
    const int* __restrict__ deg, const int* __restrict__ bsum,
    int* __restrict__ start)
{
    __shared__ int sd[256];
    int t = threadIdx.x;
    int n = blockIdx.x * 256 + t;
    int v = (n < N) ? deg[n] : 0;
    sd[t] = v;
    __syncthreads();
    #pragma unroll
    for (int off = 1; off < 256; off <<= 1) {
        int w = (t >= off) ? sd[t - off] : 0;
        __syncthreads();
        sd[t] += w;
        __syncthreads();
    }
    if (n < N) start[n] = bsum[blockIdx.x] + sd[t] - v;  // exclusive
}

// ---------------------------------------------------------------- CSR fill + rbf precompute
// rbf stored bf16 in CSR slot order: rbf_buf[slot*16 + k] = bf16(sqrt2*sin((k+1)*pi*d)/(d+eps))
__global__ __launch_bounds__(256) void fill_kernel(
    const int* __restrict__ ei, const float* __restrict__ pos,
    const int* __restrict__ start, int* __restrict__ cursor,
    int* __restrict__ csr_col, unsigned short* __restrict__ rbf_buf)
{
    int e = blockIdx.x * 256 + threadIdx.x;
    if (e >= E) return;
    int r = ei[e];
    int c = ei[E + e];
    float2 pr = reinterpret_cast<const float2*>(pos)[r];
    float2 pc = reinterpret_cast<const float2*>(pos)[c];
    float dx = pr.x - pc.x, dy = pr.y - pc.y;
    float d = sqrtf(dx * dx + dy * dy);   // pos-mean cancels
    int k = atomicAdd(&cursor[r], 1);
    int s = start[r] + k;
    csr_col[s] = c;

    // rbf via sin recurrence
    float s1 = __sinf(PI_F * d);
    float c1 = __cosf(PI_F * d);
    float inv = SQRT2_F / (d + 1e-8f);
    float tc = 2.0f * c1;
    float sk = s1, skm = 0.0f;
    unsigned int pk[8];
    #pragma unroll
    for (int i = 0; i < 8; ++i) {
        float r0 = sk * inv;
        float s2 = tc * sk - skm; skm = sk; sk = s2;
        float r1 = sk * inv;
        float s3 = tc * sk - skm; skm = sk; sk = s3;
        pk[i] = (unsigned int)f2bf(r0) | ((unsigned int)f2bf(r1) << 16);
    }
    uint4* out = reinterpret_cast<uint4*>(rbf_buf + (size_t)s * 16);
    out[0] = make_uint4(pk[0], pk[1], pk[2], pk[3]);
    out[1] = make_uint4(pk[4], pk[5], pk[6], pk[7]);
}

// ---------------------------------------------------------------- bf16 weight prep
// wt[l][n][k] = bf16(We1[l][k][n]) for k<80 else 0 ; [32 n][96 k] per layer
__global__ __launch_bounds__(256) void prep_wt_kernel(
    const float* __restrict__ We1, short* __restrict__ wt)
{
    int idx = blockIdx.x * 256 + threadIdx.x;
    if (idx >= 5 * 32 * 96) return;
    int l = idx / (32 * 96);
    int r = idx % (32 * 96);
    int n = r / 96;
    int k = r % 96;
    float v = (k < 80) ? We1[((size_t)l * 80 + k) * 32 + n] : 0.0f;
    wt[idx] = (short)f2bf(v);
}

// ---------------------------------------------------------------- node embed (writes fp32 x + bf16 xb)
__global__ __launch_bounds__(256) void node_embed_kernel(
    const float* __restrict__ u, const float* __restrict__ v,
    const float* __restrict__ bnorm, const float* __restrict__ yf,
    const float* __restrict__ Wn1, const float* __restrict__ bn1,
    const float* __restrict__ Wn2, const float* __restrict__ bn2,
    float* __restrict__ x, unsigned short* __restrict__ xb)
{
    int n = blockIdx.x * 256 + threadIdx.x;
    if (n >= N) return;

    float f[10];
    float4 uu = reinterpret_cast<const float4*>(u)[n];
    f[0] = uu.x; f[1] = uu.y; f[2] = uu.z; f[3] = uu.w;
    float4 v0 = reinterpret_cast<const float4*>(v)[2 * n];
    float4 v1 = reinterpret_cast<const float4*>(v)[2 * n + 1];
    f[4] = sqrtf(v0.x * v0.x + v0.y * v0.y);
    f[5] = sqrtf(v0.z * v0.z + v0.w * v0.w);
    f[6] = sqrtf(v1.x * v1.x + v1.y * v1.y);
    f[7] = sqrtf(v1.z * v1.z + v1.w * v1.w);
    float2 bb = reinterpret_cast<const float2*>(bnorm)[n];
    f[8] = sqrtf(bb.x * bb.x + bb.y * bb.y);
    float2 yy = reinterpret_cast<const float2*>(yf)[n];
    f[9] = sqrtf(yy.x * yy.x + yy.y * yy.y);

    float h[64];
    #pragma unroll
    for (int j = 0; j < 64; ++j) h[j] = bn1[j];
    #pragma unroll
    for (int i = 0; i < 10; ++i) {
        float t = f[i];
        #pragma unroll
        for (int j = 0; j < 64; ++j) h[j] = fmaf(t, Wn1[i * 64 + j], h[j]);
    }
    #pragma unroll
    for (int j = 0; j < 64; ++j) h[j] = silu_f(h[j]);

    float o[32];
    #pragma unroll
    for (int j = 0; j < 32; ++j) o[j] = bn2[j];
    #pragma unroll
    for (int i = 0; i < 64; ++i) {
        float t = h[i];
        #pragma unroll
        for (int j = 0; j < 32; ++j) o[j] = fmaf(t, Wn2[i * 32 + j], o[j]);
    }
    float4* xo = reinterpret_cast<float4*>(x + (size_t)n * 32);
    #pragma unroll
    for (int i = 0; i < 8; ++i)
        xo[i] = make_float4(o[4 * i], o[4 * i + 1], o[4 * i + 2], o[4 * i + 3]);

    unsigned int* xbu = reinterpret_cast<unsigned int*>(xb) + (size_t)n * 16;
    #pragma unroll
    for (int i = 0; i < 16; ++i)
        xbu[i] = (unsigned int)f2bf(o[2 * i]) | ((unsigned int)f2bf(o[2 * i + 1]) << 16);
}

// ---------------------------------------------------------------- fused layer, MFMA edge phase
// One wave per node. Edge tile: M=16 edges, K=96 = [x_row(32) | x_col(32) | rbf16+pad],
// N=32 outputs as 2 n-halves. 6 MFMA per tile. rbf fragment = precomputed bf16 load.
// All LDS is wave-private: no block barriers (intra-wave LDS ordered by lgkmcnt).
__global__ __launch_bounds__(256) void layer_kernel(
    const int* __restrict__ deg, const int* __restrict__ start,
    const int* __restrict__ csr_col, const unsigned short* __restrict__ rbf_buf,
    const float* __restrict__ x_in, const unsigned short* __restrict__ xb_in,
    float* __restrict__ x_out, unsigned short* __restrict__ xb_out,
    const short* __restrict__ wt1,   // [32][96] bf16, this layer
    const float* __restrict__ b1, const float* __restrict__ W2,
    const float* __restrict__ b2,
    const float* __restrict__ Wu1, const float* __restrict__ bu1,
    const float* __restrict__ Wu2, const float* __restrict__ bu2)
{
    __shared__ float lsh[4][32];   // per-wave sh[32]
    __shared__ float lxa[4][64];   // per-wave [x(32) | ag(32)]
    __shared__ float lhu[4][32];   // per-wave hu[32]

    int t = threadIdx.x;
    int w = t >> 6;
    int lane = t & 63;
    int quad = lane >> 4;
    int ml = lane & 15;
    int n = __builtin_amdgcn_readfirstlane(blockIdx.x * 4 + w);   // wave-uniform node

    int s0 = start[n];
    int dg = deg[n];

    // ---- preload x[n] into LDS (fp32, for node phase)
    int j32 = lane & 31;
    int half = lane >> 5;
    if (half == 0) lxa[w][j32] = x_in[(size_t)n * 32 + j32];

    // ---- B fragments: wt1[n=ml+16*h][k = ks*32 + quad*8 + 0..7], 16B each
    const short8* wp = reinterpret_cast<const short8*>(wt1);
    short8 B00 = wp[(ml     ) * 12 + 0 * 4 + quad];
    short8 B01 = wp[(ml     ) * 12 + 1 * 4 + quad];
    short8 B02 = wp[(ml     ) * 12 + 2 * 4 + quad];
    short8 B10 = wp[(ml + 16) * 12 + 0 * 4 + quad];
    short8 B11 = wp[(ml + 16) * 12 + 1 * 4 + quad];
    short8 B12 = wp[(ml + 16) * 12 + 2 * 4 + quad];

    // ---- A0 fragment: x_row (same for every edge row m)
    const short8* xbp = reinterpret_cast<const short8*>(xb_in);
    short8 A0 = xbp[(size_t)n * 4 + quad];

    float b1j0 = b1[ml];
    float b1j1 = b1[ml + 16];

    float colp0 = 0.0f, colp1 = 0.0f;
    int ntile = (dg + 15) >> 4;
    int smax = s0 + ((dg > 0) ? dg : 1) - 1;
    const short8 Z8 = {0, 0, 0, 0, 0, 0, 0, 0};

    #pragma unroll 1
    for (int tile = 0; tile < ntile; ++tile) {
        int slot = s0 + tile * 16 + ml;
        slot = min(slot, smax);                  // clamp into own range (L1-hot)
        int c = csr_col[slot];

        short8 A1 = xbp[(size_t)c * 4 + quad];   // x_col fragment

        // rbf fragment: precomputed bf16 [slot][16]; quads 2,3 are K-pad -> 0
        short8 A2 = Z8;
        if (quad < 2)
            A2 = *reinterpret_cast<const short8*>(rbf_buf + (size_t)slot * 16 + quad * 8);

        f32x4 acc0 = {0.0f, 0.0f, 0.0f, 0.0f};
        f32x4 acc1 = {0.0f, 0.0f, 0.0f, 0.0f};
        acc0 = __builtin_amdgcn_mfma_f32_16x16x32_bf16(A0, B00, acc0, 0, 0, 0);
        acc0 = __builtin_amdgcn_mfma_f32_16x16x32_bf16(A1, B01, acc0, 0, 0, 0);
        acc0 = __builtin_amdgcn_mfma_f32_16x16x32_bf16(A2, B02, acc0, 0, 0, 0);
        acc1 = __builtin_amdgcn_mfma_f32_16x16x32_bf16(A0, B10, acc1, 0, 0, 0);
        acc1 = __builtin_amdgcn_mfma_f32_16x16x32_bf16(A1, B11, acc1, 0, 0, 0);
        acc1 = __builtin_amdgcn_mfma_f32_16x16x32_bf16(A2, B12, acc1, 0, 0, 0);

        // epilogue: C row = quad*4 + r (edge), col = ml (+16). bias+silu, mask, reduce
        int rowbase = tile * 16 + quad * 4;
        #pragma unroll
        for (int r = 0; r < 4; ++r) {
            bool vld = (rowbase + r) < dg;
            float h0 = acc0[r] + b1j0;
            float h1 = acc1[r] + b1j1;
            colp0 += vld ? silu_f(h0) : 0.0f;
            colp1 += vld ? silu_f(h1) : 0.0f;
        }
    }

    // reduce over quads: all lanes end with full column sums
    colp0 += __shfl_xor(colp0, 16, 64);
    colp0 += __shfl_xor(colp0, 32, 64);
    colp1 += __shfl_xor(colp1, 16, 64);
    colp1 += __shfl_xor(colp1, 32, 64);
    if (quad == 0) {
        lsh[w][ml] = colp0;
        lsh[w][ml + 16] = colp1;
    }
    __builtin_amdgcn_wave_barrier();

    // ---- ag = (sh @ W2 + dg*b2) / max(dg,1)   (lane pair j, j+32 split k)
    float fdg = (float)dg;
    float ivd = 1.0f / fmaxf(fdg, 1.0f);
    float s = 0.0f;
    #pragma unroll
    for (int k16 = 0; k16 < 16; ++k16) {
        int k = half * 16 + k16;
        s = fmaf(lsh[w][k], W2[k * 32 + j32], s);
    }
    s += __shfl_xor(s, 32, 64);
    float ag = (s + fdg * b2[j32]) * ivd;
    if (half == 0) lxa[w][32 + j32] = ag;
    __builtin_amdgcn_wave_barrier();

    // ---- hu = silu(bu1 + [x; ag] @ Wu1)   (k split: half0 -> x rows, half1 -> ag rows)
    float s2v = 0.0f;
    #pragma unroll
    for (int k = 0; k < 32; ++k) {
        int kk = half * 32 + k;
        s2v = fmaf(lxa[w][kk], Wu1[kk * 32 + j32], s2v);
    }
    s2v += __shfl_xor(s2v, 32, 64);
    float hu = silu_f(s2v + bu1[j32]);
    if (half == 0) lhu[w][j32] = hu;
    __builtin_amdgcn_wave_barrier();

    // ---- o = bu2 + hu @ Wu2 ; x_out = x + o
    float s3 = 0.0f;
    #pragma unroll
    for (int k16 = 0; k16 < 16; ++k16) {
        int kk = half * 16 + k16;
        s3 = fmaf(lhu[w][kk], Wu2[kk * 32 + j32], s3);
    }
    s3 += __shfl_xor(s3, 32, 64);
    if (half == 0) {
        float xo = lxa[w][j32] + s3 + bu2[j32];
        x_out[(size_t)n * 32 + j32] = xo;
        xb_out[(size_t)n * 32 + j32] = f2bf(xo);
    }
}

// ---------------------------------------------------------------- LN + heads
__global__ __launch_bounds__(256) void final_kernel(
    const float* __restrict__ x, const float* __restrict__ u,
    const float* __restrict__ v,
    const float* __restrict__ ln_g, const float* __restrict__ ln_b,
    const float* __restrict__ Wr1, const float* __restrict__ br1,
    const float* __restrict__ Wr2, const float* __restrict__ br2,
    const float* __restrict__ Ws1, const float* __restrict__ bs1,
    const float* __restrict__ Ws2, const float* __restrict__ bs2,
    float* __restrict__ out)
{
    int n = blockIdx.x * 256 + threadIdx.x;
    if (n >= N) return;

    float a[32];
    const float4* x4 = reinterpret_cast<const float4*>(x + (size_t)n * 32);
    #pragma unroll
    for (int i = 0; i < 8; ++i) {
        float4 t = x4[i];
        a[4 * i] = t.x; a[4 * i + 1] = t.y; a[4 * i + 2] = t.z; a[4 * i + 3] = t.w;
    }
    float mu = 0.0f;
    #pragma unroll
    for (int i = 0; i < 32; ++i) mu += a[i];
    mu *= (1.0f / 32.0f);
    float var = 0.0f;
    #pragma unroll
    for (int i = 0; i < 32; ++i) { float dlt = a[i] - mu; var += dlt * dlt; }
    var *= (1.0f / 32.0f);
    float rs = rsqrtf(var + 1e-5f);
    #pragma unroll
    for (int i = 0; i < 32; ++i) a[i] = (a[i] - mu) * rs * ln_g[i] + ln_b[i];

    float o0 = br2[0], o1 = br2[1], o2 = bs2[0];
    #pragma unroll 1
    for (int j = 0; j < 96; ++j) {
        float hr = br1[j];
        float hs = bs1[j];
        #pragma unroll
        for (int i = 0; i < 32; ++i) {
            hr = fmaf(a[i], Wr1[i * 96 + j], hr);
            hs = fmaf(a[i], Ws1[i * 96 + j], hs);
        }
        hr = silu_f(hr);
        hs = silu_f(hs);
        o0 = fmaf(hr, Wr2[2 * j], o0);
        o1 = fmaf(hr, Wr2[2 * j + 1], o1);
        o2 = fmaf(hs, Ws2[j], o2);
    }
    out[n] = u[n * 4 + 3] + o2;
    out[N + 2 * n]     = o0 + v[n * 8 + 6];
    out[N + 2 * n + 1] = o1 + v[n * 8 + 7];
}

} // anonymous namespace

extern "C" void kernel_launch(void* const* d_in, const int* in_sizes, int n_in,
                              void* d_out, int out_size, void* d_ws, size_t ws_size,
                              hipStream_t stream)
{
    const float* u    = (const float*)d_in[0];
    const float* v    = (const float*)d_in[1];
    const float* bno  = (const float*)d_in[2];
    const float* yf   = (const float*)d_in[4];
    const float* pos  = (const float*)d_in[5];
    const int*   ei   = (const int*)d_in[6];
    const float* Wn1  = (const float*)d_in[7];
    const float* bn1  = (const float*)d_in[8];
    const float* Wn2  = (const float*)d_in[9];
    const float* bn2  = (const float*)d_in[10];
    const float* We1  = (const float*)d_in[11];
    const float* be1  = (const float*)d_in[12];
    const float* We2  = (const float*)d_in[13];
    const float* be2  = (const float*)d_in[14];
    const float* Wu1  = (const float*)d_in[15];
    const float* bu1  = (const float*)d_in[16];
    const float* Wu2  = (const float*)d_in[17];
    const float* bu2  = (const float*)d_in[18];
    const float* ln_g = (const float*)d_in[19];
    const float* ln_b = (const float*)d_in[20];
    const float* Wr1  = (const float*)d_in[21];
    const float* br1  = (const float*)d_in[22];
    const float* Wr2  = (const float*)d_in[23];
    const float* br2  = (const float*)d_in[24];
    const float* Ws1  = (const float*)d_in[25];
    const float* bs1  = (const float*)d_in[26];
    const float* Ws2  = (const float*)d_in[27];
    const float* bs2  = (const float*)d_in[28];
    float* out = (float*)d_out;

    // workspace layout (16B-aligned sections)
    int*   deg      = (int*)d_ws;                            // N
    int*   cursor   = deg + N;                               // N
    int*   start    = cursor + N;                            // N
    int*   bsum     = start + N;                             // 512
    int*   csr_col  = bsum + 512;                            // E ints
    unsigned short* rbf = (unsigned short*)(csr_col + E);    // E*16 bf16 (51.2 MB)
    float* x0       = (float*)(rbf + (size_t)E * 16);        // N*32 f32
    float* x1       = x0 + (size_t)N * S;                    // N*32 f32
    unsigned short* xb0 = (unsigned short*)(x1 + (size_t)N * S);   // N*32 bf16
    unsigned short* xb1 = xb0 + (size_t)N * S;               // N*32 bf16
    short* wt       = (short*)(xb1 + (size_t)N * S);         // 5*32*96 bf16

    const int egrid = (E + 255) / 256;

    hipMemsetAsync(deg, 0, 2 * N * sizeof(int), stream);   // deg + cursor
    deg_kernel<<<egrid, 256, 0, stream>>>(ei, deg);
    scanA<<<NB, 256, 0, stream>>>(deg, bsum);
    scanB<<<1, 512, 0, stream>>>(bsum);
    scanC<<<NB, 256, 0, stream>>>(deg, bsum, start);
    fill_kernel<<<egrid, 256, 0, stream>>>(ei, pos, start, cursor, csr_col, rbf);
    prep_wt_kernel<<<60, 256, 0, stream>>>(We1, wt);

    node_embed_kernel<<<NB, 256, 0, stream>>>(u, v, bno, yf, Wn1, bn1, Wn2, bn2,
                                              x0, xb0);

    float* xin = x0;  float* xout = x1;
    unsigned short* xbin = xb0;  unsigned short* xbout = xb1;
    for (int l = 0; l < L; ++l) {
        layer_kernel<<<N / 4, 256, 0, stream>>>(
            deg, start, csr_col, rbf, xin, xbin, xout, xbout,
            wt + (size_t)l * 32 * 96,
            be1 + (size_t)l * 32,
            We2 + (size_t)l * 32 * 32, be2 + (size_t)l * 32,
            Wu1 + (size_t)l * 64 * 32, bu1 + (size_t)l * 32,
            Wu2 + (size_t)l * 32 * 32, bu2 + (size_t)l * 32);
        float* tf = xin; xin = xout; xout = tf;
        unsigned short* tb = xbin; xbin = xbout; xbout = tb;
    }

    final_kernel<<<NB, 256, 0, stream>>>(xin, u, v, ln_g, ln_b,
                                         Wr1, br1, Wr2, br2,
                                         Ws1, bs1, Ws2, bs2, out);
}

// Round 7
// 708.844 us; speedup vs baseline: 20.1548x; 1.4190x over previous
//
#include <hip/hip_runtime.h>
#include <cmath>

namespace {

constexpr int N = 100000;
constexpr int E = 1600000;
constexpr int S = 32;           // hidden
constexpr int L = 5;            // layers
constexpr int NB = (N + 255) / 256;   // node-per-thread kernels
constexpr int NPW = 16;               // nodes per wave in layer kernel
constexpr int LB2 = (N + 63) / 64;    // 1563 blocks (4 waves/block, 16 nodes/wave)
constexpr float PI_F    = 3.14159265358979323846f;
constexpr float SQRT2_F = 1.41421356237309515f;

typedef __attribute__((ext_vector_type(8))) short short8;   // 8 x bf16
typedef __attribute__((ext_vector_type(4))) float f32x4;

__device__ __forceinline__ float silu_f(float x) {
    return x / (1.0f + __expf(-x));
}

// float -> bf16 bits, round-to-nearest-even
__device__ __forceinline__ unsigned short f2bf(float f) {
    unsigned int u = __float_as_uint(f);
    u = (u + 0x7FFFu + ((u >> 16) & 1u)) >> 16;
    return (unsigned short)u;
}

__device__ __forceinline__ int rl(int v, int i) {
    return __builtin_amdgcn_readlane(v, i);
}

// advance (i,t) to the next tile of this wave's 16-node batch (uniform)
__device__ __forceinline__ void adv(int& i, int& t, int vd) {
    ++t;
    while (i < 16) {
        int dgi = rl(vd, i);
        int nt = (dgi + 15) >> 4;
        if (t < nt) break;
        t = 0; ++i;
    }
}

// CSR slot for (i,t) at lane row ml; clamped into the node's own range
__device__ __forceinline__ int slotOf(int i, int t, int vs, int vd, int ml) {
    if (i >= 16) return 0;
    int s0 = rl(vs, i);
    int dg = rl(vd, i);
    int smax = s0 + ((dg > 0) ? dg : 1) - 1;
    int s = s0 + t * 16 + ml;
    return min(s, smax);
}

// ---------------------------------------------------------------- degree count
__global__ __launch_bounds__(256) void deg_kernel(
    const int* __restrict__ ei, int* __restrict__ deg)
{
    int e = blockIdx.x * 256 + threadIdx.x;
    if (e >= E) return;
    atomicAdd(&deg[ei[e]], 1);
}

// ---------------------------------------------------------------- scan (3-kernel hierarchical)
__global__ __launch_bounds__(256) void scanA(
    const int* __restrict__ deg, int* __restrict__ bsum)
{
    __shared__ int sd[256];
    int t = threadIdx.x;
    int n = blockIdx.x * 256 + t;
    sd[t] = (n < N) ? deg[n] : 0;
    __syncthreads();
    #pragma unroll
    for (int s = 128; s > 0; s >>= 1) {
        if (t < s) sd[t] += sd[t + s];
        __syncthreads();
    }
    if (t == 0) bsum[blockIdx.x] = sd[0];
}

__global__ __launch_bounds__(512) void scanB(int* __restrict__ bsum)
{
    __shared__ int sd[512];
    int t = threadIdx.x;
    sd[t] = (t < NB) ? bsum[t] : 0;
    __syncthreads();
    #pragma unroll
    for (int off = 1; off < 512; off <<= 1) {
        int v = (t >= off) ? sd[t - off] : 0;
        __syncthreads();
        sd[t] += v;
        __syncthreads();
    }
    if (t < NB) bsum[t] = (t == 0) ? 0 : sd[t - 1];   // exclusive
}

__global__ __launch_bounds__(256) void scanC(
    const int* __restrict__ deg, const int* __restrict__ bsum,
    int* __restrict__ start)
{
    __shared__ int sd[256];
    int t = threadIdx.x;
    int n = blockIdx.x * 256 + t;
    int v = (n < N) ? deg[n] : 0;
    sd[t] = v;
    __syncthreads();
    #pragma unroll
    for (int off = 1; off < 256; off <<= 1) {
        int w = (t >= off) ? sd[t - off] : 0;
        __syncthreads();
        sd[t] += w;
        __syncthreads();
    }
    if (n < N) start[n] = bsum[blockIdx.x] + sd[t] - v;  // exclusive
}

// ---------------------------------------------------------------- CSR fill + rbf precompute
__global__ __launch_bounds__(256) void fill_kernel(
    const int* __restrict__ ei, const float* __restrict__ pos,
    const int* __restrict__ start, int* __restrict__ cursor,
    int* __restrict__ csr_col, unsigned short* __restrict__ rbf_buf)
{
    int e = blockIdx.x * 256 + threadIdx.x;
    if (e >= E) return;
    int r = ei[e];
    int c = ei[E + e];
    float2 pr = reinterpret_cast<const float2*>(pos)[r];
    float2 pc = reinterpret_cast<const float2*>(pos)[c];
    float dx = pr.x - pc.x, dy = pr.y - pc.y;
    float d = sqrtf(dx * dx + dy * dy);   // pos-mean cancels
    int k = atomicAdd(&cursor[r], 1);
    int s = start[r] + k;
    csr_col[s] = c;

    float s1 = __sinf(PI_F * d);
    float c1 = __cosf(PI_F * d);
    float inv = SQRT2_F / (d + 1e-8f);
    float tc = 2.0f * c1;
    float sk = s1, skm = 0.0f;
    unsigned int pk[8];
    #pragma unroll
    for (int i = 0; i < 8; ++i) {
        float r0 = sk * inv;
        float s2 = tc * sk - skm; skm = sk; sk = s2;
        float r1 = sk * inv;
        float s3 = tc * sk - skm; skm = sk; sk = s3;
        pk[i] = (unsigned int)f2bf(r0) | ((unsigned int)f2bf(r1) << 16);
    }
    uint4* out = reinterpret_cast<uint4*>(rbf_buf + (size_t)s * 16);
    out[0] = make_uint4(pk[0], pk[1], pk[2], pk[3]);
    out[1] = make_uint4(pk[4], pk[5], pk[6], pk[7]);
}

// ---------------------------------------------------------------- bf16 weight prep (transposed [n][k])
__global__ __launch_bounds__(256) void prep_wt_kernel(
    const float* __restrict__ We1, const float* __restrict__ We2,
    const float* __restrict__ Wu1, const float* __restrict__ Wu2,
    short* __restrict__ wt1, short* __restrict__ wt2,
    short* __restrict__ wtu1, short* __restrict__ wtu2)
{
    int idx = blockIdx.x * 256 + threadIdx.x;
    if (idx < 5 * 32 * 96) {
        int l = idx / (32 * 96), r = idx % (32 * 96), n = r / 96, k = r % 96;
        float v = (k < 80) ? We1[((size_t)l * 80 + k) * 32 + n] : 0.0f;
        wt1[idx] = (short)f2bf(v);
    }
    if (idx < 5 * 32 * 32) {
        int l = idx / 1024, r = idx % 1024, n = r / 32, k = r % 32;
        wt2[idx]  = (short)f2bf(We2[((size_t)l * 32 + k) * 32 + n]);
        wtu2[idx] = (short)f2bf(Wu2[((size_t)l * 32 + k) * 32 + n]);
    }
    if (idx < 5 * 32 * 64) {
        int l = idx / 2048, r = idx % 2048, n = r / 64, k = r % 64;
        wtu1[idx] = (short)f2bf(Wu1[((size_t)l * 64 + k) * 32 + n]);
    }
}

// ---------------------------------------------------------------- node embed (writes fp32 x + bf16 xb)
__global__ __launch_bounds__(256) void node_embed_kernel(
    const float* __restrict__ u, const float* __restrict__ v,
    const float* __restrict__ bnorm, const float* __restrict__ yf,
    const float* __restrict__ Wn1, const float* __restrict__ bn1,
    const float* __restrict__ Wn2, const float* __restrict__ bn2,
    float* __restrict__ x, unsigned short* __restrict__ xb)
{
    int n = blockIdx.x * 256 + threadIdx.x;
    if (n >= N) return;

    float f[10];
    float4 uu = reinterpret_cast<const float4*>(u)[n];
    f[0] = uu.x; f[1] = uu.y; f[2] = uu.z; f[3] = uu.w;
    float4 v0 = reinterpret_cast<const float4*>(v)[2 * n];
    float4 v1 = reinterpret_cast<const float4*>(v)[2 * n + 1];
    f[4] = sqrtf(v0.x * v0.x + v0.y * v0.y);
    f[5] = sqrtf(v0.z * v0.z + v0.w * v0.w);
    f[6] = sqrtf(v1.x * v1.x + v1.y * v1.y);
    f[7] = sqrtf(v1.z * v1.z + v1.w * v1.w);
    float2 bb = reinterpret_cast<const float2*>(bnorm)[n];
    f[8] = sqrtf(bb.x * bb.x + bb.y * bb.y);
    float2 yy = reinterpret_cast<const float2*>(yf)[n];
    f[9] = sqrtf(yy.x * yy.x + yy.y * yy.y);

    float h[64];
    #pragma unroll
    for (int j = 0; j < 64; ++j) h[j] = bn1[j];
    #pragma unroll
    for (int i = 0; i < 10; ++i) {
        float t = f[i];
        #pragma unroll
        for (int j = 0; j < 64; ++j) h[j] = fmaf(t, Wn1[i * 64 + j], h[j]);
    }
    #pragma unroll
    for (int j = 0; j < 64; ++j) h[j] = silu_f(h[j]);

    float o[32];
    #pragma unroll
    for (int j = 0; j < 32; ++j) o[j] = bn2[j];
    #pragma unroll
    for (int i = 0; i < 64; ++i) {
        float t = h[i];
        #pragma unroll
        for (int j = 0; j < 32; ++j) o[j] = fmaf(t, Wn2[i * 32 + j], o[j]);
    }
    float4* xo = reinterpret_cast<float4*>(x + (size_t)n * 32);
    #pragma unroll
    for (int i = 0; i < 8; ++i)
        xo[i] = make_float4(o[4 * i], o[4 * i + 1], o[4 * i + 2], o[4 * i + 3]);

    unsigned int* xbu = reinterpret_cast<unsigned int*>(xb) + (size_t)n * 16;
    #pragma unroll
    for (int i = 0; i < 16; ++i)
        xbu[i] = (unsigned int)f2bf(o[2 * i]) | ((unsigned int)f2bf(o[2 * i + 1]) << 16);
}

// ---------------------------------------------------------------- fused layer v2
// One wave = 16 consecutive nodes. Edge phase: per-node 16-edge MFMA tiles with a
// 2-deep software pipeline (csr_col 2 ahead, xb/rbf/A0 frags 1 ahead). Node phase:
// the 16-node batch runs sh@W2, [x,ag]@Wu1, hu@Wu2 as 8 MFMAs with bf16 LDS hops.
__global__ __launch_bounds__(256, 4) void layer_kernel(
    const int* __restrict__ deg, const int* __restrict__ start,
    const int* __restrict__ csr_col, const unsigned short* __restrict__ rbf_buf,
    const float* __restrict__ x_in, const unsigned short* __restrict__ xb_in,
    float* __restrict__ x_out, unsigned short* __restrict__ xb_out,
    const short* __restrict__ wt1, const float* __restrict__ b1,
    const short* __restrict__ wt2, const float* __restrict__ b2,
    const short* __restrict__ wtu1, const float* __restrict__ bu1,
    const short* __restrict__ wtu2, const float* __restrict__ bu2)
{
    __shared__ unsigned short lsh[4][16 * 34];   // sh  (bf16), stride 34
    __shared__ unsigned short agb[4][16 * 34];   // ag  (bf16)
    __shared__ unsigned short hub[4][16 * 34];   // hu  (bf16)
    __shared__ float lx[4][16 * 33];             // x   (fp32), stride 33
    __shared__ float ldg[4][16];
    __shared__ float livd[4][16];

    int t = threadIdx.x;
    int w = t >> 6;
    int lane = t & 63;
    int quad = lane >> 4;
    int ml = lane & 15;
    int wid = blockIdx.x * 4 + w;
    int nbase = __builtin_amdgcn_readfirstlane(wid * NPW);
    if (nbase >= N) return;   // N % 16 == 0, so valid waves own full batches

    // ---- batch metadata: lane ml holds node ml's start/deg
    int vs = start[nbase + ml];
    int vd = deg[nbase + ml];

    // ---- edge-phase B fragments (wt1 [32][96])
    const short8* wp = reinterpret_cast<const short8*>(wt1);
    short8 B00 = wp[(ml     ) * 12 + 0 * 4 + quad];
    short8 B01 = wp[(ml     ) * 12 + 1 * 4 + quad];
    short8 B02 = wp[(ml     ) * 12 + 2 * 4 + quad];
    short8 B10 = wp[(ml + 16) * 12 + 0 * 4 + quad];
    short8 B11 = wp[(ml + 16) * 12 + 1 * 4 + quad];
    short8 B12 = wp[(ml + 16) * 12 + 2 * 4 + quad];

    const short8* xbp = reinterpret_cast<const short8*>(xb_in);
    // node-phase x A-fragment (A[m=node ml][k=quad*8+j]) — prefetch now
    short8 Ax = xbp[(size_t)(nbase + ml) * 4 + quad];

    float b1j0 = b1[ml];
    float b1j1 = b1[ml + 16];

    // ---- zero sh, preload x into LDS, stash deg floats
    unsigned short* lshp = lsh[w];
    for (int k = lane; k < 16 * 34; k += 64) lshp[k] = 0;
    {
        const float* xs = x_in + (size_t)nbase * 32;
        float* lxp = lx[w];
        #pragma unroll
        for (int k = 0; k < 8; ++k) {
            int idx = lane * 8 + k;
            lxp[(idx >> 5) * 33 + (idx & 31)] = xs[idx];
        }
    }
    if (lane < 16) {
        ldg[w][lane] = (float)vd;
        livd[w][lane] = 1.0f / fmaxf((float)vd, 1.0f);
    }

    // ---- software-pipelined edge loop
    const short8 Z8 = {0, 0, 0, 0, 0, 0, 0, 0};
    int i0 = 0, t0 = -1; adv(i0, t0, vd);
    int i1 = i0, t1 = t0; adv(i1, t1, vd);
    int i2 = i1, t2 = t1; adv(i2, t2, vd);

    int slot0 = slotOf(i0, t0, vs, vd, ml);
    int slot1 = slotOf(i1, t1, vs, vd, ml);
    int colCur  = csr_col[slot0];
    int colNext = csr_col[slot1];
    short8 A1c = xbp[(size_t)colCur * 4 + quad];
    short8 A2c = Z8;
    if (quad < 2) A2c = *reinterpret_cast<const short8*>(rbf_buf + (size_t)slot0 * 16 + quad * 8);
    short8 A0c = xbp[(size_t)(nbase + min(i0, 15)) * 4 + quad];

    float colp0 = 0.0f, colp1 = 0.0f;
    while (i0 < 16) {
        // stage 2: col two ahead
        int slot2 = slotOf(i2, t2, vs, vd, ml);
        int colNN = csr_col[slot2];
        // stage 1: fragments one ahead
        short8 A1n = xbp[(size_t)colNext * 4 + quad];
        short8 A2n = Z8;
        if (quad < 2) A2n = *reinterpret_cast<const short8*>(rbf_buf + (size_t)slot1 * 16 + quad * 8);
        short8 A0n = xbp[(size_t)(nbase + min(i1, 15)) * 4 + quad];

        // stage 0: compute current tile
        f32x4 acc0 = {0.0f, 0.0f, 0.0f, 0.0f};
        f32x4 acc1 = {0.0f, 0.0f, 0.0f, 0.0f};
        acc0 = __builtin_amdgcn_mfma_f32_16x16x32_bf16(A0c, B00, acc0, 0, 0, 0);
        acc0 = __builtin_amdgcn_mfma_f32_16x16x32_bf16(A1c, B01, acc0, 0, 0, 0);
        acc0 = __builtin_amdgcn_mfma_f32_16x16x32_bf16(A2c, B02, acc0, 0, 0, 0);
        acc1 = __builtin_amdgcn_mfma_f32_16x16x32_bf16(A0c, B10, acc1, 0, 0, 0);
        acc1 = __builtin_amdgcn_mfma_f32_16x16x32_bf16(A1c, B11, acc1, 0, 0, 0);
        acc1 = __builtin_amdgcn_mfma_f32_16x16x32_bf16(A2c, B12, acc1, 0, 0, 0);

        int dg0 = rl(vd, i0);
        int rowbase = t0 * 16 + quad * 4;
        #pragma unroll
        for (int r = 0; r < 4; ++r) {
            bool vld = (rowbase + r) < dg0;
            float h0 = acc0[r] + b1j0;
            float h1 = acc1[r] + b1j1;
            colp0 += vld ? silu_f(h0) : 0.0f;
            colp1 += vld ? silu_f(h1) : 0.0f;
        }
        if (t0 == ((dg0 + 15) >> 4) - 1) {   // last tile of node i0 (uniform)
            colp0 += __shfl_xor(colp0, 16, 64);
            colp0 += __shfl_xor(colp0, 32, 64);
            colp1 += __shfl_xor(colp1, 16, 64);
            colp1 += __shfl_xor(colp1, 32, 64);
            if (quad == 0) {
                lshp[i0 * 34 + ml]      = f2bf(colp0);
                lshp[i0 * 34 + ml + 16] = f2bf(colp1);
            }
            colp0 = 0.0f; colp1 = 0.0f;
        }

        // rotate pipeline
        A0c = A0n; A1c = A1n; A2c = A2n;
        colNext = colNN; slot1 = slot2;
        i0 = i1; t0 = t1; i1 = i2; t1 = t2;
        adv(i2, t2, vd);
    }
    __builtin_amdgcn_wave_barrier();

    // ---- node phase: 16-node batch, 8 MFMAs
    const short8* w2p = reinterpret_cast<const short8*>(wt2);
    short8 Bw2_0 = w2p[(ml     ) * 4 + quad];
    short8 Bw2_1 = w2p[(ml + 16) * 4 + quad];
    const short8* u1p = reinterpret_cast<const short8*>(wtu1);
    short8 Bu1_00 = u1p[(ml     ) * 8 + quad];       // k 0..31 (x)
    short8 Bu1_10 = u1p[(ml     ) * 8 + 4 + quad];   // k 32..63 (ag)
    short8 Bu1_01 = u1p[(ml + 16) * 8 + quad];
    short8 Bu1_11 = u1p[(ml + 16) * 8 + 4 + quad];
    const short8* u2p = reinterpret_cast<const short8*>(wtu2);
    short8 Bu2_0 = u2p[(ml     ) * 4 + quad];
    short8 Bu2_1 = u2p[(ml + 16) * 4 + quad];

    // sh @ W2
    short8 Ash = *reinterpret_cast<const short8*>(lshp + ml * 34 + quad * 8);
    f32x4 c0 = {0.0f, 0.0f, 0.0f, 0.0f};
    f32x4 c1 = {0.0f, 0.0f, 0.0f, 0.0f};
    c0 = __builtin_amdgcn_mfma_f32_16x16x32_bf16(Ash, Bw2_0, c0, 0, 0, 0);
    c1 = __builtin_amdgcn_mfma_f32_16x16x32_bf16(Ash, Bw2_1, c1, 0, 0, 0);
    float b2c0 = b2[ml], b2c1 = b2[ml + 16];
    unsigned short* agp = agb[w];
    int row = quad * 4;
    #pragma unroll
    for (int r = 0; r < 4; ++r) {
        float fd = ldg[w][row + r];
        float iv = livd[w][row + r];
        agp[(row + r) * 34 + ml]      = f2bf((c0[r] + fd * b2c0) * iv);
        agp[(row + r) * 34 + ml + 16] = f2bf((c1[r] + fd * b2c1) * iv);
    }
    __builtin_amdgcn_wave_barrier();

    // [x ; ag] @ Wu1
    short8 Aag = *reinterpret_cast<const short8*>(agp + ml * 34 + quad * 8);
    f32x4 d0 = {0.0f, 0.0f, 0.0f, 0.0f};
    f32x4 d1 = {0.0f, 0.0f, 0.0f, 0.0f};
    d0 = __builtin_amdgcn_mfma_f32_16x16x32_bf16(Ax,  Bu1_00, d0, 0, 0, 0);
    d0 = __builtin_amdgcn_mfma_f32_16x16x32_bf16(Aag, Bu1_10, d0, 0, 0, 0);
    d1 = __builtin_amdgcn_mfma_f32_16x16x32_bf16(Ax,  Bu1_01, d1, 0, 0, 0);
    d1 = __builtin_amdgcn_mfma_f32_16x16x32_bf16(Aag, Bu1_11, d1, 0, 0, 0);
    float bu1c0 = bu1[ml], bu1c1 = bu1[ml + 16];
    unsigned short* hup = hub[w];
    #pragma unroll
    for (int r = 0; r < 4; ++r) {
        hup[(row + r) * 34 + ml]      = f2bf(silu_f(d0[r] + bu1c0));
        hup[(row + r) * 34 + ml + 16] = f2bf(silu_f(d1[r] + bu1c1));
    }
    __builtin_amdgcn_wave_barrier();

    // hu @ Wu2 ; residual + store
    short8 Ahu = *reinterpret_cast<const short8*>(hup + ml * 34 + quad * 8);
    f32x4 e0 = {0.0f, 0.0f, 0.0f, 0.0f};
    f32x4 e1 = {0.0f, 0.0f, 0.0f, 0.0f};
    e0 = __builtin_amdgcn_mfma_f32_16x16x32_bf16(Ahu, Bu2_0, e0, 0, 0, 0);
    e1 = __builtin_amdgcn_mfma_f32_16x16x32_bf16(Ahu, Bu2_1, e1, 0, 0, 0);
    float bu2c0 = bu2[ml], bu2c1 = bu2[ml + 16];
    #pragma unroll
    for (int r = 0; r < 4; ++r) {
        int nn = nbase + row + r;
        float o0 = e0[r] + bu2c0 + lx[w][(row + r) * 33 + ml];
        float o1 = e1[r] + bu2c1 + lx[w][(row + r) * 33 + ml + 16];
        x_out[(size_t)nn * 32 + ml]      = o0;
        x_out[(size_t)nn * 32 + ml + 16] = o1;
        xb_out[(size_t)nn * 32 + ml]      = f2bf(o0);
        xb_out[(size_t)nn * 32 + ml + 16] = f2bf(o1);
    }
}

// ---------------------------------------------------------------- LN + heads
__global__ __launch_bounds__(256) void final_kernel(
    const float* __restrict__ x, const float* __restrict__ u,
    const float* __restrict__ v,
    const float* __restrict__ ln_g, const float* __restrict__ ln_b,
    const float* __restrict__ Wr1, const float* __restrict__ br1,
    const float* __restrict__ Wr2, const float* __restrict__ br2,
    const float* __restrict__ Ws1, const float* __restrict__ bs1,
    const float* __restrict__ Ws2, const float* __restrict__ bs2,
    float* __restrict__ out)
{
    int n = blockIdx.x * 256 + threadIdx.x;
    if (n >= N) return;

    float a[32];
    const float4* x4 = reinterpret_cast<const float4*>(x + (size_t)n * 32);
    #pragma unroll
    for (int i = 0; i < 8; ++i) {
        float4 t = x4[i];
        a[4 * i] = t.x; a[4 * i + 1] = t.y; a[4 * i + 2] = t.z; a[4 * i + 3] = t.w;
    }
    float mu = 0.0f;
    #pragma unroll
    for (int i = 0; i < 32; ++i) mu += a[i];
    mu *= (1.0f / 32.0f);
    float var = 0.0f;
    #pragma unroll
    for (int i = 0; i < 32; ++i) { float dlt = a[i] - mu; var += dlt * dlt; }
    var *= (1.0f / 32.0f);
    float rs = rsqrtf(var + 1e-5f);
    #pragma unroll
    for (int i = 0; i < 32; ++i) a[i] = (a[i] - mu) * rs * ln_g[i] + ln_b[i];

    float o0 = br2[0], o1 = br2[1], o2 = bs2[0];
    #pragma unroll 1
    for (int j = 0; j < 96; ++j) {
        float hr = br1[j];
        float hs = bs1[j];
        #pragma unroll
        for (int i = 0; i < 32; ++i) {
            hr = fmaf(a[i], Wr1[i * 96 + j], hr);
            hs = fmaf(a[i], Ws1[i * 96 + j], hs);
        }
        hr = silu_f(hr);
        hs = silu_f(hs);
        o0 = fmaf(hr, Wr2[2 * j], o0);
        o1 = fmaf(hr, Wr2[2 * j + 1], o1);
        o2 = fmaf(hs, Ws2[j], o2);
    }
    out[n] = u[n * 4 + 3] + o2;
    out[N + 2 * n]     = o0 + v[n * 8 + 6];
    out[N + 2 * n + 1] = o1 + v[n * 8 + 7];
}

} // anonymous namespace

extern "C" void kernel_launch(void* const* d_in, const int* in_sizes, int n_in,
                              void* d_out, int out_size, void* d_ws, size_t ws_size,
                              hipStream_t stream)
{
    const float* u    = (const float*)d_in[0];
    const float* v    = (const float*)d_in[1];
    const float* bno  = (const float*)d_in[2];
    const float* yf   = (const float*)d_in[4];
    const float* pos  = (const float*)d_in[5];
    const int*   ei   = (const int*)d_in[6];
    const float* Wn1  = (const float*)d_in[7];
    const float* bn1  = (const float*)d_in[8];
    const float* Wn2  = (const float*)d_in[9];
    const float* bn2  = (const float*)d_in[10];
    const float* We1  = (const float*)d_in[11];
    const float* be1  = (const float*)d_in[12];
    const float* We2  = (const float*)d_in[13];
    const float* be2  = (const float*)d_in[14];
    const float* Wu1  = (const float*)d_in[15];
    const float* bu1  = (const float*)d_in[16];
    const float* Wu2  = (const float*)d_in[17];
    const float* bu2  = (const float*)d_in[18];
    const float* ln_g = (const float*)d_in[19];
    const float* ln_b = (const float*)d_in[20];
    const float* Wr1  = (const float*)d_in[21];
    const float* br1  = (const float*)d_in[22];
    const float* Wr2  = (const float*)d_in[23];
    const float* br2  = (const float*)d_in[24];
    const float* Ws1  = (const float*)d_in[25];
    const float* bs1  = (const float*)d_in[26];
    const float* Ws2  = (const float*)d_in[27];
    const float* bs2  = (const float*)d_in[28];
    float* out = (float*)d_out;

    // workspace layout (16B-aligned sections)
    int*   deg      = (int*)d_ws;                            // N
    int*   cursor   = deg + N;                               // N
    int*   start    = cursor + N;                            // N
    int*   bsum     = start + N;                             // 512
    int*   csr_col  = bsum + 512;                            // E ints
    unsigned short* rbf = (unsigned short*)(csr_col + E);    // E*16 bf16 (51.2 MB)
    float* x0       = (float*)(rbf + (size_t)E * 16);        // N*32 f32
    float* x1       = x0 + (size_t)N * S;                    // N*32 f32
    unsigned short* xb0 = (unsigned short*)(x1 + (size_t)N * S);   // N*32 bf16
    unsigned short* xb1 = xb0 + (size_t)N * S;               // N*32 bf16
    short* wt1      = (short*)(xb1 + (size_t)N * S);         // 5*32*96
    short* wt2      = wt1 + 5 * 32 * 96;                     // 5*32*32
    short* wtu1     = wt2 + 5 * 32 * 32;                     // 5*32*64
    short* wtu2     = wtu1 + 5 * 32 * 64;                    // 5*32*32

    const int egrid = (E + 255) / 256;

    hipMemsetAsync(deg, 0, 2 * N * sizeof(int), stream);   // deg + cursor
    deg_kernel<<<egrid, 256, 0, stream>>>(ei, deg);
    scanA<<<NB, 256, 0, stream>>>(deg, bsum);
    scanB<<<1, 512, 0, stream>>>(bsum);
    scanC<<<NB, 256, 0, stream>>>(deg, bsum, start);
    fill_kernel<<<egrid, 256, 0, stream>>>(ei, pos, start, cursor, csr_col, rbf);
    prep_wt_kernel<<<60, 256, 0, stream>>>(We1, We2, Wu1, Wu2, wt1, wt2, wtu1, wtu2);

    node_embed_kernel<<<NB, 256, 0, stream>>>(u, v, bno, yf, Wn1, bn1, Wn2, bn2,
                                              x0, xb0);

    float* xin = x0;  float* xout = x1;
    unsigned short* xbin = xb0;  unsigned short* xbout = xb1;
    for (int l = 0; l < L; ++l) {
        layer_kernel<<<LB2, 256, 0, stream>>>(
            deg, start, csr_col, rbf, xin, xbin, xout, xbout,
            wt1 + (size_t)l * 32 * 96,  be1 + (size_t)l * 32,
            wt2 + (size_t)l * 32 * 32,  be2 + (size_t)l * 32,
            wtu1 + (size_t)l * 32 * 64, bu1 + (size_t)l * 32,
            wtu2 + (size_t)l * 32 * 32, bu2 + (size_t)l * 32);
        float* tf = xin; xin = xout; xout = tf;
        unsigned short* tb = xbin; xbin = xbout; xbout = tb;
    }

    final_kernel<<<NB, 256, 0, stream>>>(xin, u, v, ln_g, ln_b,
                                         Wr1, br1, Wr2, br2,
                                         Ws1, bs1, Ws2, bs2, out);
}